// Round 7
// baseline (252.016 us; speedup 1.0000x reference)
//
#include <hip/hip_runtime.h>

// ---------------------------------------------------------------------------
// MHA: out = softmax_causal((xWq)(xWk)^T / sqrt(64)) (xWv) Wo
// B=4 T=2048 D=1024 H=16 Dh=64.  All matmuls in bf16 MFMA (fp32 accum).
// R15: GEMM line closed (matrix complete: 8ph/1blk 68.0 is best) -> QKV
// reverted to R4 gemm_qkvT; Wo stays on 4-phase gemm8<1> (~16us).  attn:
// R11's chunk-interleave put a P LDS write->read round-trip (~200cy) on the
// critical path of EVERY chunk.  Fix: double-buffered per-wave P
// (2x[32][36]) + chunk software pipeline QKT(c+1) || PV(c) -> P-write
// latency hides under PV MFMAs, softmax VALU overlaps matrix pipe (T15),
// setprio(1) around PV cluster (T5).  LDS 75.25KB -> still 2 blocks/CU.
// ---------------------------------------------------------------------------

typedef short  short8  __attribute__((ext_vector_type(8)));
typedef short  short4v __attribute__((ext_vector_type(4)));
typedef float  floatx4 __attribute__((ext_vector_type(4)));
typedef unsigned uint2v __attribute__((ext_vector_type(2)));

#define T_SZ 2048
#define DM   1024

// 0.125 (Dh^-0.5) * log2(e): softmax in base-2 domain -> native v_exp_f32
#define QSCALE 0.18033688011112042f

__device__ __forceinline__ short f2bf(float f) {
  unsigned u = __float_as_uint(f);
  u += 0x7fffu + ((u >> 16) & 1u);        // RNE
  return (short)(u >> 16);
}

#if defined(__has_builtin) && __has_builtin(__builtin_amdgcn_cvt_pk_bf16_f32)
typedef __bf16 bf16x2_t __attribute__((ext_vector_type(2)));
__device__ __forceinline__ unsigned pack_bf(float lo, float hi) {   // 1 VALU op
  return __builtin_bit_cast(unsigned, __builtin_amdgcn_cvt_pk_bf16_f32(lo, hi));
}
#else
__device__ __forceinline__ unsigned pack_bf(float lo, float hi) {   // 3 VALU ops
  return __builtin_amdgcn_perm(__float_as_uint(hi) + 0x8000u,
                               __float_as_uint(lo) + 0x8000u, 0x07060302u);
}
#endif

#if defined(__has_builtin) && __has_builtin(__builtin_amdgcn_exp2f)
__device__ __forceinline__ float fexp2(float x) { return __builtin_amdgcn_exp2f(x); }
#else
__device__ __forceinline__ float fexp2(float x) { return exp2f(x); }
#endif

__device__ __forceinline__ void gll16(const void* g, void* l) {
  __builtin_amdgcn_global_load_lds((const __attribute__((address_space(1))) void*)g,
                                   (__attribute__((address_space(3))) void*)l, 16, 0, 0);
}

#define SBAR() asm volatile("s_barrier" ::: "memory")
#define WLG()  asm volatile("s_waitcnt lgkmcnt(0)" ::: "memory")
#define WV6()  asm volatile("s_waitcnt vmcnt(6)" ::: "memory")
#define WV0()  asm volatile("s_waitcnt vmcnt(0)" ::: "memory")

// -------------------------------------------------- converts, one launch
// z in [0,4): W[z] fp32 [K,N] -> bf16 W^T [N,K]   (grid x,y = 32,32; block 32x8)
// z == 4   : x fp32 -> bf16 flat
__global__ void cvt_kernel(const float* __restrict__ s0, const float* __restrict__ s1,
                           const float* __restrict__ s2, const float* __restrict__ s3,
                           short* __restrict__ dst,
                           const float* __restrict__ x, short* __restrict__ xb) {
  const int tx = threadIdx.x, ty = threadIdx.y;       // block (32,8)
  if (blockIdx.z == 4) {                              // ---- x -> bf16
    const int tid = ty * 32 + tx;
    const int blk = blockIdx.y * 32 + blockIdx.x;     // 0..1023
    int i = (blk * 256 + tid) * 4;
#pragma unroll
    for (int j = 0; j < 8; ++j) {
      const float4 v = *(const float4*)(x + i);
      short4v o;
      o.x = f2bf(v.x); o.y = f2bf(v.y); o.z = f2bf(v.z); o.w = f2bf(v.w);
      *(short4v*)(xb + i) = o;
      i += 1048576;
    }
    return;
  }
  const float* srcs[4] = {s0, s1, s2, s3};
  const float* src = srcs[blockIdx.z];
  short* d = dst + (size_t)blockIdx.z * 1048576;
  __shared__ float tile[32][33];
  const int n_base = blockIdx.x * 32, k_base = blockIdx.y * 32;
#pragma unroll
  for (int j = 0; j < 4; ++j)
    tile[ty + j * 8][tx] = src[(size_t)(k_base + ty + j * 8) * 1024 + n_base + tx];
  __syncthreads();
#pragma unroll
  for (int j = 0; j < 4; ++j)
    d[(size_t)(n_base + ty + j * 8) * 1024 + k_base + tx] = f2bf(tile[tx][ty + j * 8]);
}

// -------------------------------------------------- QKV GEMM, transposed 8-phase
// C^T = Wt[3072,1024] * xb[8192,1024]^T.  512 thr (8 waves, 2M x 4N), BK=64.
// BM=128 (W rows m0), BN=256 (tokens n0).  768 blocks = 3 clean rounds
// @ 1 block/CU (96 KB LDS).  R4-measured best (68.0us).
__global__ __launch_bounds__(512, 2) void gemm_qkvT(
    const short* __restrict__ Wt, const short* __restrict__ xb,
    short* __restrict__ obf, short* __restrict__ vt) {
  __shared__ short As[2 * 128 * 64];   // [slot][128][64]  32 KB (Wt tile)
  __shared__ short Bs[2 * 256 * 64];   // [slot][256][64]  64 KB (x tile)
  const int tid  = threadIdx.x;
  const int w    = tid >> 6, lane = tid & 63;
  const int quad = lane >> 4, l15 = lane & 15;
  const int wr   = w >> 2, wc = w & 3;          // 2 (M=128) x 4 (N=256)
  const int fx   = l15 & 7;
  const int lid  = (int)blockIdx.x;             // 768
  const int xcd  = lid & 7, idx = lid >> 3;     // idx in [0,96)
  const int m0   = (idx >> 2) * 128;            // 24 W-row tiles
  const int n0   = (xcd * 4 + (idx & 3)) * 256; // token tile
  const int srow = tid >> 3;
  const int scol = ((tid & 7) ^ (srow & 7)) * 8;

  const short* Ag = Wt + (size_t)(m0 + srow) * 1024 + scol;
  const short* Bg = xb + (size_t)(n0 + srow) * 1024 + scol;

  floatx4 acc[4][4] = {};
  short8 af[2][2], bf[4][2];

#define STG_A(slot, kb) do { \
    short* _lb = &As[(slot) * 8192 + tid * 8]; \
    gll16(Ag + (kb), _lb); \
    gll16(Ag + (size_t)(64 * 1024) + (kb), _lb + 4096); \
  } while (0)
#define STG_B(slot, h, kb) do { \
    short* _lb = &Bs[(slot) * 16384 + (h) * 8192 + tid * 8]; \
    const short* _gp = Bg + (size_t)(h) * (128 * 1024) + (kb); \
    gll16(_gp, _lb); \
    gll16(_gp + (size_t)(64 * 1024), _lb + 4096); \
  } while (0)
#define LDA2(slot, ih) do { \
    _Pragma("unroll") for (int ii = 0; ii < 2; ++ii) \
    _Pragma("unroll") for (int s = 0; s < 2; ++s) \
      af[ii][s] = *(const short8*)&As[(slot) * 8192 + \
          (wr * 64 + (ih) * 32 + ii * 16 + l15) * 64 + ((s * 4 + quad) ^ fx) * 8]; \
  } while (0)
#define LDB8(slot) do { \
    _Pragma("unroll") for (int j = 0; j < 4; ++j) \
    _Pragma("unroll") for (int s = 0; s < 2; ++s) \
      bf[j][s] = *(const short8*)&Bs[(slot) * 16384 + \
          (wc * 64 + j * 16 + l15) * 64 + ((s * 4 + quad) ^ fx) * 8]; \
  } while (0)
#define MMQ(ih, jh) do { \
    __builtin_amdgcn_s_setprio(1); \
    _Pragma("unroll") for (int ii = 0; ii < 2; ++ii) \
    _Pragma("unroll") for (int jj = 0; jj < 2; ++jj) \
    _Pragma("unroll") for (int s = 0; s < 2; ++s) \
      acc[(ih) * 2 + ii][(jh) * 2 + jj] = __builtin_amdgcn_mfma_f32_16x16x32_bf16( \
          af[ii][s], bf[(jh) * 2 + jj][s], acc[(ih) * 2 + ii][(jh) * 2 + jj], 0, 0, 0); \
    __builtin_amdgcn_s_setprio(0); \
  } while (0)

  // prologue: kt0 -> slot0, kt1 -> slot1 (12 loads); WV6 -> kt0's 6 landed.
  STG_B(0, 0, 0);  STG_B(0, 1, 0);  STG_A(0, 0);
  STG_B(1, 0, 64); STG_B(1, 1, 64); STG_A(1, 64);
  WV6(); SBAR();

  for (int t = 0; t < 8; ++t) {
    const int kn2 = (2 * t + 2) * 64;          // -> slot0
    const int kn3 = (2 * t + 3) * 64;          // -> slot1
    const bool mre = (t < 7);
    // ---- p1: read kt0 frags (i-half0 + all B)
    LDA2(0, 0); LDB8(0);
    SBAR(); WLG(); MMQ(0, 0); SBAR();
    // ---- p2
    if (mre) STG_B(0, 0, kn2);
    SBAR(); MMQ(0, 1); SBAR();
    // ---- p3
    LDA2(0, 1);
    if (mre) STG_B(0, 1, kn2);
    SBAR(); WLG(); MMQ(1, 0); SBAR();
    // ---- p4
    if (mre) { STG_A(0, kn2); WV6(); } else { WV0(); }
    SBAR(); MMQ(1, 1); SBAR();
    // ---- p5: read kt1 frags
    LDA2(1, 0); LDB8(1);
    SBAR(); WLG(); MMQ(0, 0); SBAR();
    // ---- p6
    if (mre) STG_B(1, 0, kn3);
    SBAR(); MMQ(0, 1); SBAR();
    // ---- p7
    LDA2(1, 1);
    if (mre) STG_B(1, 1, kn3);
    SBAR(); WLG(); MMQ(1, 0); SBAR();
    // ---- p8
    if (mre) { STG_A(1, kn3); WV6(); }
    SBAR(); MMQ(1, 1); SBAR();
  }

  // ---- epilogue: C^T[m=qkv col][n=token]; head-dim on quad/r -> packed Q/K.
  const int wsel = m0 >> 10;                    // 0=Q 1=K 2=V, uniform/block
  const int nn0  = (m0 & 1023) + wr * 64;
  if (wsel < 2) {
    const float scale = (wsel == 0) ? QSCALE : 1.0f;
    short* outw = obf + (size_t)wsel * (64u * 2048u * 64u);
#pragma unroll
    for (int i = 0; i < 4; ++i) {
      const int nn = nn0 + i * 16 + quad * 4;   // qkv col, mult of 4
      const int h = nn >> 6, d = nn & 63;
#pragma unroll
      for (int j = 0; j < 4; ++j) {
        const int tg = n0 + wc * 64 + j * 16 + l15;
        const int b = tg >> 11, tt = tg & 2047;
        short4v o4;
#pragma unroll
        for (int r = 0; r < 4; ++r) o4[r] = f2bf(acc[i][j][r] * scale);
        *(short4v*)(outw + (((size_t)(b * 16 + h) * 2048 + tt) << 6) + d) = o4;
      }
    }
  } else {
#pragma unroll
    for (int i = 0; i < 4; ++i) {
      const int nn = nn0 + i * 16 + quad * 4;   // v col in [0,1024)
      const int h = nn >> 6, d = nn & 63;
#pragma unroll
      for (int j = 0; j < 4; ++j) {
        const int tg = n0 + wc * 64 + j * 16 + l15;
        const int b = tg >> 11, tt = tg & 2047;
#pragma unroll
        for (int r = 0; r < 4; ++r)
          vt[(((size_t)(b * 16 + h) * 64 + d + r) << 11) + tt] = f2bf(acc[i][j][r]);
      }
    }
  }
#undef STG_A
#undef STG_B
#undef LDA2
#undef LDB8
#undef MMQ
}

// -------------------------------------------------- transposed GEMM, 4-phase (Wo)
// C^T = A[M,1024] * B[N,1024]^T, tile 128(m) x 256(n), BK=64, 512 thr.
// MODE 1 (Wo): grid 256 = 1.0 round, fp32 float4 epilogue.  R5-measured.
template <int MODE>
__global__ __launch_bounds__(512, 2) void gemm8(
    const short* __restrict__ A, const short* __restrict__ B,
    short* __restrict__ obf, short* __restrict__ vt, float* __restrict__ of) {
  __shared__ short As[2 * 128 * 64];   // [slot][128][64]  32 KB
  __shared__ short Bs[2 * 256 * 64];   // [slot][256][64]  64 KB
  const int tid  = threadIdx.x;
  const int w    = tid >> 6, lane = tid & 63;
  const int quad = lane >> 4, l15 = lane & 15;
  const int wr   = w >> 2, wc = w & 3;          // 2 (M=128) x 4 (N=256)
  const int fx   = l15 & 7;
  const int lid  = (int)blockIdx.x;
  const int xcd  = lid & 7, idx = lid >> 3;
  const int m0   = (idx >> 2) * 128;
  const int n0   = (xcd * 4 + (idx & 3)) * 256;
  const int srow = tid >> 3;
  const int scol = ((tid & 7) ^ (srow & 7)) * 8;

  const short* Ag = A + (size_t)(m0 + srow) * 1024 + scol;
  const short* Bg = B + (size_t)(n0 + srow) * 1024 + scol;

  floatx4 acc[4][4] = {};
  short8 af[4][2], bf[4][2];

#define STG_A(slot, kb) do { \
    short* _lb = &As[(slot) * 8192 + tid * 8]; \
    const short* _gp = Ag + (kb); \
    gll16(_gp, _lb); \
    gll16(_gp + (size_t)(64 * 1024), _lb + 4096); \
  } while (0)
#define STG_B(slot, kb) do { \
    short* _lb = &Bs[(slot) * 16384 + tid * 8]; \
    const short* _gp = Bg + (kb); \
    gll16(_gp,                         _lb); \
    gll16(_gp + (size_t)( 64 * 1024), _lb + 4096); \
    gll16(_gp + (size_t)(128 * 1024), _lb + 8192); \
    gll16(_gp + (size_t)(192 * 1024), _lb + 12288); \
  } while (0)
#define LDA_ALL(slot) do { \
    _Pragma("unroll") for (int ii = 0; ii < 4; ++ii) \
    _Pragma("unroll") for (int s = 0; s < 2; ++s) \
      af[ii][s] = *(const short8*)&As[(slot) * 8192 + \
          (wr * 64 + ii * 16 + l15) * 64 + ((s * 4 + quad) ^ fx) * 8]; \
  } while (0)
#define LDB_ALL(slot) do { \
    _Pragma("unroll") for (int j = 0; j < 4; ++j) \
    _Pragma("unroll") for (int s = 0; s < 2; ++s) \
      bf[j][s] = *(const short8*)&Bs[(slot) * 16384 + \
          (wc * 64 + j * 16 + l15) * 64 + ((s * 4 + quad) ^ fx) * 8]; \
  } while (0)
#define MMH(ih) do { \
    __builtin_amdgcn_s_setprio(1); \
    _Pragma("unroll") for (int i2 = 0; i2 < 2; ++i2) \
    _Pragma("unroll") for (int j = 0; j < 4; ++j) \
    _Pragma("unroll") for (int s = 0; s < 2; ++s) \
      acc[(ih) * 2 + i2][j] = __builtin_amdgcn_mfma_f32_16x16x32_bf16( \
          af[(ih) * 2 + i2][s], bf[j][s], acc[(ih) * 2 + i2][j], 0, 0, 0); \
    __builtin_amdgcn_s_setprio(0); \
  } while (0)

  STG_B(0, 0);  STG_A(0, 0);
  STG_B(1, 64); STG_A(1, 64);
  WV6(); SBAR();

  for (int t = 0; t < 8; ++t) {
    const int kn2 = (2 * t + 2) * 64;          // -> slot0
    const int kn3 = (2 * t + 3) * 64;          // -> slot1
    const bool mre = (t < 7);
    LDA_ALL(0); LDB_ALL(0);
    SBAR(); WLG();
    MMH(0);
    SBAR();
    if (mre) STG_B(0, kn2);
    if (mre) STG_A(0, kn2);
    MMH(1);
    if (mre) WV6(); else WV0();
    SBAR();
    LDA_ALL(1); LDB_ALL(1);
    SBAR(); WLG();
    MMH(0);
    SBAR();
    if (mre) STG_B(1, kn3);
    if (mre) STG_A(1, kn3);
    MMH(1);
    if (mre) WV6();
    SBAR();
  }

  if constexpr (MODE == 0) {
    const int wsel = m0 >> 10;
    const int nn0  = (m0 & 1023) + wr * 64;
    if (wsel < 2) {
      const float scale = (wsel == 0) ? QSCALE : 1.0f;
      short* outw = obf + (size_t)wsel * (64u * 2048u * 64u);
#pragma unroll
      for (int i = 0; i < 4; ++i) {
        const int nn = nn0 + i * 16 + quad * 4;
        const int h = nn >> 6, d = nn & 63;
#pragma unroll
        for (int j = 0; j < 4; ++j) {
          const int tg = n0 + wc * 64 + j * 16 + l15;
          const int b = tg >> 11, tt = tg & 2047;
          short4v o4;
#pragma unroll
          for (int r = 0; r < 4; ++r) o4[r] = f2bf(acc[i][j][r] * scale);
          *(short4v*)(outw + (((size_t)(b * 16 + h) * 2048 + tt) << 6) + d) = o4;
        }
      }
    } else {
#pragma unroll
      for (int i = 0; i < 4; ++i) {
        const int nn = nn0 + i * 16 + quad * 4;
        const int h = nn >> 6, d = nn & 63;
#pragma unroll
        for (int j = 0; j < 4; ++j) {
          const int tg = n0 + wc * 64 + j * 16 + l15;
          const int b = tg >> 11, tt = tg & 2047;
#pragma unroll
          for (int r = 0; r < 4; ++r)
            vt[(((size_t)(b * 16 + h) * 64 + d + r) << 11) + tt] = f2bf(acc[i][j][r]);
        }
      }
    }
  } else {
    const int nn0 = m0 + wr * 64;
#pragma unroll
    for (int i = 0; i < 4; ++i) {
      const int nn = nn0 + i * 16 + quad * 4;    // out col, 16B aligned
#pragma unroll
      for (int j = 0; j < 4; ++j) {
        const int tg = n0 + wc * 64 + j * 16 + l15;
        float4 o4;
        o4.x = acc[i][j][0]; o4.y = acc[i][j][1];
        o4.z = acc[i][j][2]; o4.w = acc[i][j][3];
        *(float4*)(of + (size_t)tg * 1024 + nn) = o4;
      }
    }
  }
#undef STG_A
#undef STG_B
#undef LDA_ALL
#undef LDB_ALL
#undef MMH
}

// -------------------------------------------------- flash attention (causal, transposed)
// grid (8, 64), block 512 (8 waves), 2 blocks/CU.  Block = one 256-row
// q-band; waves own 32 q rows (strips A/B of 16, kf/vf reads feed both).
// R15: per-wave P double-buffered (2x[32][36]); chunk pipeline
// QKT(c+1) || PV(c) takes the P LDS write->read round-trip off the
// critical path; setprio(1) around the PV MFMA cluster.
__global__ __launch_bounds__(512, 4) void attn_kernel(
    const short* __restrict__ Qg, const short* __restrict__ Kg,
    const short* __restrict__ Vt, short* __restrict__ ctx) {
  __shared__ short Ks[128 * 72];        // [t_k][d]                    18.00 KB
  __shared__ short Vs[80 * 136];        // [d][t_k], row 64 = ones     21.25 KB
  __shared__ short Ps[8 * 2 * 32 * 36]; // per-wave dbuf [2][32][36]   36.00 KB

  const int tid  = threadIdx.x;
  const int w    = tid >> 6, lane = tid & 63;
  const int quad = lane >> 4, l15 = lane & 15;
  const int bh = (int)blockIdx.x + 8 * ((int)blockIdx.y & 7);
  const int g  = (int)blockIdx.y >> 3;
  const int qb = (g < 4) ? (7 - g) : (g - 4);   // CU pairs get qb + (7-qb)
  const int b  = bh >> 4, h = bh & 15;

  const size_t base = (size_t)bh * (T_SZ * 64);
  const short* Qb  = Qg + base;
  const short* Kb  = Kg + base;
  const short* Vtb = Vt + base;
  short* Pw = &Ps[w * 2304];            // 2 bufs x 32 x 36

  // staging (512 thr): K row skr, 32B at col skp; V row svr, 32B at col svp
  const int skr = tid >> 2, skp = (tid & 3) * 16;
  const int svr = tid >> 3, svp = (tid & 7) * 16;

  // init Vs rows 64..79: row 64 = 1.0 (l-reduction), 65..79 = 0
  if (tid < 256) {
    const int rr = 64 + (tid >> 4), cb = (tid & 15) * 8;
    const short vv = (tid < 16) ? (short)0x3F80 : (short)0;
    short8 fill;
#pragma unroll
    for (int j = 0; j < 8; ++j) fill[j] = vv;
    *(short8*)&Vs[rr * 136 + cb] = fill;
  }

  const int rowA = qb * 256 + w * 32;          // strip A (16 q), strip B = +16
  const int rowB = rowA + 16;
  const int ktmax = 2 * qb + 2;

  const short8 qA0 = *(const short8*)(Qb + (size_t)(rowA + l15) * 64 + quad * 8);
  const short8 qA1 = *(const short8*)(Qb + (size_t)(rowA + l15) * 64 + 32 + quad * 8);
  const short8 qB0 = *(const short8*)(Qb + (size_t)(rowB + l15) * 64 + quad * 8);
  const short8 qB1 = *(const short8*)(Qb + (size_t)(rowB + l15) * 64 + 32 + quad * 8);

  floatx4 OA[4] = {}, OB[4] = {};
  floatx4 O5A = {}, O5B = {};                  // row: l in quad0/reg0

  // preload tile 0 into registers
  short8 kR[2], vR[2];
  kR[0] = *(const short8*)(Kb + (size_t)skr * 64 + skp);
  kR[1] = *(const short8*)(Kb + (size_t)skr * 64 + skp + 8);
  vR[0] = *(const short8*)(Vtb + (size_t)svr * 2048 + svp);
  vR[1] = *(const short8*)(Vtb + (size_t)svr * 2048 + svp + 8);

  for (int kt = 0; kt < ktmax; ++kt) {
    const int k0 = kt << 7;
    __syncthreads();                           // prior tile's LDS reads done
    *(short8*)&Ks[skr * 72 + skp]     = kR[0];
    *(short8*)&Ks[skr * 72 + skp + 8] = kR[1];
    *(short8*)&Vs[svr * 136 + svp]     = vR[0];
    *(short8*)&Vs[svr * 136 + svp + 8] = vR[1];
    if (kt + 1 < ktmax) {                      // prefetch next tile
      const int kn = (kt + 1) << 7;
      kR[0] = *(const short8*)(Kb + (size_t)(kn + skr) * 64 + skp);
      kR[1] = *(const short8*)(Kb + (size_t)(kn + skr) * 64 + skp + 8);
      vR[0] = *(const short8*)(Vtb + (size_t)svr * 2048 + kn + svp);
      vR[1] = *(const short8*)(Vtb + (size_t)svr * 2048 + kn + svp + 8);
    }
    __syncthreads();                           // staged LDS visible

    const int dkA = rowA - k0;                 // wave-uniform
    if (dkA < 0) continue;                     // tail: wave idle, barriers done
    const int dkB = dkA + 16;
    const int limA = dkA + l15, limB = limA + 16;
    const int naA = min(8, (dkA >> 4) + 1), nchA = (naA + 1) >> 1;
    const int naB = min(8, (dkB >> 4) + 1), nchB = (naB + 1) >> 1;

    // ---- QK^T for chunk c (2 mt-tiles) -> P buf at pb0
    auto QKT = [&](int c, int pb0) {
#pragma unroll
      for (int mm = 0; mm < 2; ++mm) {
        const int mt = 2 * c + mm;
        const int pa = pb0 + l15 * 36 + mm * 16 + quad * 4;          // strip A
        const int pb = pb0 + (16 + l15) * 36 + mm * 16 + quad * 4;   // strip B
        const bool aB = (mt * 16 < dkB + 16);
        const bool aA = (mt * 16 < dkA + 16);
        if (aB) {
          const short8 kf0 = *(const short8*)&Ks[(mt * 16 + l15) * 72 + quad * 8];
          const short8 kf1 = *(const short8*)&Ks[(mt * 16 + l15) * 72 + 32 + quad * 8];
          {                                    // ---- strip B
            floatx4 s = {};
            s = __builtin_amdgcn_mfma_f32_16x16x32_bf16(kf0, qB0, s, 0, 0, 0);
            s = __builtin_amdgcn_mfma_f32_16x16x32_bf16(kf1, qB1, s, 0, 0, 0);
            if (mt * 16 + 15 > dkB) {
#pragma unroll
              for (int r = 0; r < 4; ++r)
                if (mt * 16 + quad * 4 + r > limB) s[r] = -1e30f;
            }
            floatx4 e;
#pragma unroll
            for (int r = 0; r < 4; ++r) e[r] = fexp2(s[r]);
            uint2v pd;
            pd.x = pack_bf(e[0], e[1]);
            pd.y = pack_bf(e[2], e[3]);
            *(uint2v*)&Pw[pb] = pd;
          }
          if (c < nchA) {                      // ---- strip A (reuses kf)
            if (aA) {
              floatx4 s = {};
              s = __builtin_amdgcn_mfma_f32_16x16x32_bf16(kf0, qA0, s, 0, 0, 0);
              s = __builtin_amdgcn_mfma_f32_16x16x32_bf16(kf1, qA1, s, 0, 0, 0);
              if (mt * 16 + 15 > dkA) {
#pragma unroll
                for (int r = 0; r < 4; ++r)
                  if (mt * 16 + quad * 4 + r > limA) s[r] = -1e30f;
              }
              floatx4 e;
#pragma unroll
              for (int r = 0; r < 4; ++r) e[r] = fexp2(s[r]);
              uint2v pd;
              pd.x = pack_bf(e[0], e[1]);
              pd.y = pack_bf(e[2], e[3]);
              *(uint2v*)&Pw[pa] = pd;
            } else {
              uint2v z; z.x = 0; z.y = 0;
              *(uint2v*)&Pw[pa] = z;
            }
          }
        } else {                               // aB false => aA false (mm==1)
          uint2v z; z.x = 0; z.y = 0;
          *(uint2v*)&Pw[pb] = z;
          if (c < nchA) *(uint2v*)&Pw[pa] = z;
        }
      }
    };

    // ---- PV for chunk c from P buf at pb0
    auto PV = [&](int c, int pb0) {
      const int vcol = c * 32 + quad * 8;
      const short8 vfl = *(const short8*)&Vs[(64 + l15) * 136 + vcol];
      short8 vf[4];
#pragma unroll
      for (int dt = 0; dt < 4; ++dt)
        vf[dt] = *(const short8*)&Vs[(dt * 16 + l15) * 136 + vcol];
      const short8 pfB = *(const short8*)&Pw[pb0 + (16 + l15) * 36 + quad * 8];
      __builtin_amdgcn_s_setprio(1);
#pragma unroll
      for (int dt = 0; dt < 4; ++dt)
        OB[dt] = __builtin_amdgcn_mfma_f32_16x16x32_bf16(vf[dt], pfB, OB[dt], 0, 0, 0);
      O5B = __builtin_amdgcn_mfma_f32_16x16x32_bf16(vfl, pfB, O5B, 0, 0, 0);
      if (c < nchA) {                          // reuses vf/vfl
        const short8 pfA = *(const short8*)&Pw[pb0 + l15 * 36 + quad * 8];
#pragma unroll
        for (int dt = 0; dt < 4; ++dt)
          OA[dt] = __builtin_amdgcn_mfma_f32_16x16x32_bf16(vf[dt], pfA, OA[dt], 0, 0, 0);
        O5A = __builtin_amdgcn_mfma_f32_16x16x32_bf16(vfl, pfA, O5A, 0, 0, 0);
      }
      __builtin_amdgcn_s_setprio(0);
    };

    // ---- chunk software pipeline: QKT(c+1) hides under PV(c)
    QKT(0, 0);                                 // nchB >= 1 when dkA >= 0
#pragma unroll
    for (int c = 0; c < 4; ++c) {
      if (c < nchB) {
        if (c + 1 < nchB) QKT(c + 1, ((c + 1) & 1) * 1152);
        PV(c, (c & 1) * 1152);
      }
    }
  }

  // epilogue: l = O5[0] of quad0 lane l15 (C-layout row 0 = ones-row d=64)
  {
    const float lA = __shfl(O5A[0], l15);
    const float invA = 1.0f / lA;
    const int t = rowA + l15;
    short* cb = ctx + (((size_t)(b * T_SZ + t)) << 10) + h * 64 + quad * 4;
#pragma unroll
    for (int dt = 0; dt < 4; ++dt) {
      short4v o4;
#pragma unroll
      for (int r = 0; r < 4; ++r) o4[r] = f2bf(OA[dt][r] * invA);
      *(short4v*)(cb + dt * 16) = o4;
    }
  }
  {
    const float lB = __shfl(O5B[0], l15);
    const float invB = 1.0f / lB;
    const int t = rowB + l15;
    short* cb = ctx + (((size_t)(b * T_SZ + t)) << 10) + h * 64 + quad * 4;
#pragma unroll
    for (int dt = 0; dt < 4; ++dt) {
      short4v o4;
#pragma unroll
      for (int r = 0; r < 4; ++r) o4[r] = f2bf(OB[dt][r] * invB);
      *(short4v*)(cb + dt * 16) = o4;
    }
  }
}

// --------------------------------------------------
extern "C" void kernel_launch(void* const* d_in, const int* in_sizes, int n_in,
                              void* d_out, int out_size, void* d_ws, size_t ws_size,
                              hipStream_t stream) {
  const float* x  = (const float*)d_in[0];
  const float* Wq = (const float*)d_in[1];
  const float* Wk = (const float*)d_in[2];
  const float* Wv = (const float*)d_in[3];
  const float* Wo = (const float*)d_in[4];
  float* out = (float*)d_out;

  // bf16 workspace (72 MB):
  //   xb [8M]  : x bf16; dead after gemm_qkvT -> reused as ctx
  //   Wt [4x1M]: transposed weights
  //   Qb,Kb [8M each] : projections [bh][t][64]
  //   Vt [8M]  : V^T [bh][64][t]  (written directly by gemm_qkvT epilogue)
  short* ws  = (short*)d_ws;
  short* xb  = ws;
  short* Wt  = ws + 8388608;
  short* Qb  = Wt + 4 * 1048576;
  short* Kb  = Qb + 8388608;
  short* Vt  = Kb + 8388608;
  short* ctx = xb;

  cvt_kernel<<<dim3(32, 32, 5), dim3(32, 8), 0, stream>>>(Wq, Wk, Wv, Wo, Wt, x, xb);
  gemm_qkvT<<<dim3(768), 512, 0, stream>>>(Wt, xb, Qb, Vt);
  attn_kernel<<<dim3(8, 64), 512, 0, stream>>>(Qb, Kb, Vt, ctx);
  gemm8<1><<<dim3(256), 512, 0, stream>>>(Wt + 3 * 1048576, ctx, nullptr, nullptr, out);
}

// Round 8
// 245.126 us; speedup vs baseline: 1.0281x; 1.0281x over previous
//
#include <hip/hip_runtime.h>

// ---------------------------------------------------------------------------
// MHA: out = softmax_causal((xWq)(xWk)^T / sqrt(64)) (xWv) Wo
// B=4 T=2048 D=1024 H=16 Dh=64.  All matmuls in bf16 MFMA (fp32 accum).
// R16 (base = R5 best 236.7): QKV persistent 3-rep.  Wo and QKV ran the
// SAME per-block kernel at 16 vs 24.1 us/round -> ~8us/round of inter-round
// drain + exposed epilogue at 1 block/CU.  gemm_qkv3: 256 blocks = 1.0
// round; each block runs the 4-phase BK=64 K-loop 3x (rep = Q,K,V panel,
// same token panel -> B L2-hot).  At t=7 the p2/p4 stage bursts source the
// NEXT rep's A (same vmcnt ledger as steady state -> pipeline never drains);
// Q/K epilogues issue between stage and WV6 -> hidden.  attn (R5-exact):
// vfl ones-row frag is data-independent -> constant reg frag; Vs shrunk to
// [64][136], init block deleted.
// ---------------------------------------------------------------------------

typedef short  short8  __attribute__((ext_vector_type(8)));
typedef short  short4v __attribute__((ext_vector_type(4)));
typedef float  floatx4 __attribute__((ext_vector_type(4)));
typedef unsigned uint2v __attribute__((ext_vector_type(2)));

#define T_SZ 2048
#define DM   1024

// 0.125 (Dh^-0.5) * log2(e): softmax in base-2 domain -> native v_exp_f32
#define QSCALE 0.18033688011112042f

__device__ __forceinline__ short f2bf(float f) {
  unsigned u = __float_as_uint(f);
  u += 0x7fffu + ((u >> 16) & 1u);        // RNE
  return (short)(u >> 16);
}

#if defined(__has_builtin) && __has_builtin(__builtin_amdgcn_cvt_pk_bf16_f32)
typedef __bf16 bf16x2_t __attribute__((ext_vector_type(2)));
__device__ __forceinline__ unsigned pack_bf(float lo, float hi) {   // 1 VALU op
  return __builtin_bit_cast(unsigned, __builtin_amdgcn_cvt_pk_bf16_f32(lo, hi));
}
#else
__device__ __forceinline__ unsigned pack_bf(float lo, float hi) {   // 3 VALU ops
  return __builtin_amdgcn_perm(__float_as_uint(hi) + 0x8000u,
                               __float_as_uint(lo) + 0x8000u, 0x07060302u);
}
#endif

#if defined(__has_builtin) && __has_builtin(__builtin_amdgcn_exp2f)
__device__ __forceinline__ float fexp2(float x) { return __builtin_amdgcn_exp2f(x); }
#else
__device__ __forceinline__ float fexp2(float x) { return exp2f(x); }
#endif

__device__ __forceinline__ void gll16(const void* g, void* l) {
  __builtin_amdgcn_global_load_lds((const __attribute__((address_space(1))) void*)g,
                                   (__attribute__((address_space(3))) void*)l, 16, 0, 0);
}

#define SBAR() asm volatile("s_barrier" ::: "memory")
#define WLG()  asm volatile("s_waitcnt lgkmcnt(0)" ::: "memory")
#define WV6()  asm volatile("s_waitcnt vmcnt(6)" ::: "memory")
#define WV0()  asm volatile("s_waitcnt vmcnt(0)" ::: "memory")

// -------------------------------------------------- converts, one launch
// z in [0,4): W[z] fp32 [K,N] -> bf16 W^T [N,K]   (grid x,y = 32,32; block 32x8)
// z == 4   : x fp32 -> bf16 flat
__global__ void cvt_kernel(const float* __restrict__ s0, const float* __restrict__ s1,
                           const float* __restrict__ s2, const float* __restrict__ s3,
                           short* __restrict__ dst,
                           const float* __restrict__ x, short* __restrict__ xb) {
  const int tx = threadIdx.x, ty = threadIdx.y;       // block (32,8)
  if (blockIdx.z == 4) {                              // ---- x -> bf16
    const int tid = ty * 32 + tx;
    const int blk = blockIdx.y * 32 + blockIdx.x;     // 0..1023
    int i = (blk * 256 + tid) * 4;
#pragma unroll
    for (int j = 0; j < 8; ++j) {
      const float4 v = *(const float4*)(x + i);
      short4v o;
      o.x = f2bf(v.x); o.y = f2bf(v.y); o.z = f2bf(v.z); o.w = f2bf(v.w);
      *(short4v*)(xb + i) = o;
      i += 1048576;
    }
    return;
  }
  const float* srcs[4] = {s0, s1, s2, s3};
  const float* src = srcs[blockIdx.z];
  short* d = dst + (size_t)blockIdx.z * 1048576;
  __shared__ float tile[32][33];
  const int n_base = blockIdx.x * 32, k_base = blockIdx.y * 32;
#pragma unroll
  for (int j = 0; j < 4; ++j)
    tile[ty + j * 8][tx] = src[(size_t)(k_base + ty + j * 8) * 1024 + n_base + tx];
  __syncthreads();
#pragma unroll
  for (int j = 0; j < 4; ++j)
    d[(size_t)(n_base + ty + j * 8) * 1024 + k_base + tx] = f2bf(tile[tx][ty + j * 8]);
}

// -------------------------------------------------- QKV GEMM, persistent 3-rep
// C^T = Wt[3072,1024] * xb[8192,1024]^T.  Tile 128(m) x 256(n), BK=64,
// 512 thr (8 waves 2Mx4N, 64x64 each), 96 KB LDS, 1 block/CU.
// grid 256 = 1.0 round; block computes reps 0,1,2 = Q,K,V panels for its
// (m_base, n0): m0 = rep*1024 + m_base, same n0 (B panel L2-hot).
// Per t-iter (4-phase): p1 read slot0 | MMH(0); p2 stage slot0<-next |
// MMH(1) | WV6; p3/p4 mirror slot1.  At t==7 the stage source is the NEXT
// rep's A at kb 0/64 -> identical vmcnt ledger, no drain across reps.
// Q/K epilogue issues at t==7 p4 between stage burst and WV6 (hidden).
__global__ __launch_bounds__(512, 2) void gemm_qkv3(
    const short* __restrict__ Wt, const short* __restrict__ xb,
    short* __restrict__ obf, short* __restrict__ vt) {
  __shared__ short As[2 * 128 * 64];   // [slot][128][64]  32 KB
  __shared__ short Bs[2 * 256 * 64];   // [slot][256][64]  64 KB
  const int tid  = threadIdx.x;
  const int w    = tid >> 6, lane = tid & 63;
  const int quad = lane >> 4, l15 = lane & 15;
  const int wr   = w >> 2, wc = w & 3;          // 2 (M=128) x 4 (N=256)
  const int fx   = l15 & 7;
  const int lid  = (int)blockIdx.x;             // 256
  const int xcd  = lid & 7, idx = lid >> 3;     // idx in [0,32)
  const int m_base = (idx >> 2) * 128;          // 8 m-tiles per panel
  const int n0   = (xcd * 4 + (idx & 3)) * 256; // token tile (per-XCD panel)
  const int srow = tid >> 3;
  const int scol = ((tid & 7) ^ (srow & 7)) * 8;

  const short* Ag = Wt + (size_t)(m_base + srow) * 1024 + scol;
  const short* Bg = xb + (size_t)(n0 + srow) * 1024 + scol;

  floatx4 acc[4][4] = {};
  short8 af[4][2], bf[4][2];

#define STG_A(slot, kb, base) do { \
    short* _lb = &As[(slot) * 8192 + tid * 8]; \
    const short* _gp = (base) + (kb); \
    gll16(_gp, _lb); \
    gll16(_gp + (size_t)(64 * 1024), _lb + 4096); \
  } while (0)
#define STG_B(slot, kb) do { \
    short* _lb = &Bs[(slot) * 16384 + tid * 8]; \
    const short* _gp = Bg + (kb); \
    gll16(_gp,                         _lb); \
    gll16(_gp + (size_t)( 64 * 1024), _lb + 4096); \
    gll16(_gp + (size_t)(128 * 1024), _lb + 8192); \
    gll16(_gp + (size_t)(192 * 1024), _lb + 12288); \
  } while (0)
#define LDA_ALL(slot) do { \
    _Pragma("unroll") for (int ii = 0; ii < 4; ++ii) \
    _Pragma("unroll") for (int s = 0; s < 2; ++s) \
      af[ii][s] = *(const short8*)&As[(slot) * 8192 + \
          (wr * 64 + ii * 16 + l15) * 64 + ((s * 4 + quad) ^ fx) * 8]; \
  } while (0)
#define LDB_ALL(slot) do { \
    _Pragma("unroll") for (int j = 0; j < 4; ++j) \
    _Pragma("unroll") for (int s = 0; s < 2; ++s) \
      bf[j][s] = *(const short8*)&Bs[(slot) * 16384 + \
          (wc * 64 + j * 16 + l15) * 64 + ((s * 4 + quad) ^ fx) * 8]; \
  } while (0)
#define MMH(ih) do { \
    __builtin_amdgcn_s_setprio(1); \
    _Pragma("unroll") for (int i2 = 0; i2 < 2; ++i2) \
    _Pragma("unroll") for (int j = 0; j < 4; ++j) \
    _Pragma("unroll") for (int s = 0; s < 2; ++s) \
      acc[(ih) * 2 + i2][j] = __builtin_amdgcn_mfma_f32_16x16x32_bf16( \
          af[(ih) * 2 + i2][s], bf[j][s], acc[(ih) * 2 + i2][j], 0, 0, 0); \
    __builtin_amdgcn_s_setprio(0); \
  } while (0)

  // prologue: rep0 kt0 -> slot0, kt1 -> slot1; WV6 -> slot0 landed.
  STG_B(0, 0);  STG_A(0, 0, Ag);
  STG_B(1, 64); STG_A(1, 64, Ag);
  WV6(); SBAR();

  for (int rep = 0; rep < 3; ++rep) {
    const int nn0 = m_base + wr * 64;           // out-col base within panel
    for (int t = 0; t < 8; ++t) {
      const bool wrap = (t == 7);
      const bool last = (rep == 2) && wrap;
      const short* Asrc = wrap ? (Ag + 1048576) : Ag;  // next rep's panel
      const int kb2 = wrap ? 0  : (2 * t + 2) * 64;    // -> slot0
      const int kb3 = wrap ? 64 : (2 * t + 3) * 64;    // -> slot1
      // ---- p1: read all slot0 frags, compute M-half 0
      LDA_ALL(0); LDB_ALL(0);
      SBAR(); WLG();
      MMH(0);
      SBAR();
      // ---- p2: stage slot0 <- next, compute M-half 1
      if (!last) { STG_B(0, kb2); STG_A(0, kb2, Asrc); }
      MMH(1);
      if (!last) WV6(); else WV0();
      SBAR();
      // ---- p3: read all slot1 frags, compute M-half 0
      LDA_ALL(1); LDB_ALL(1);
      SBAR(); WLG();
      MMH(0);
      SBAR();
      // ---- p4: stage slot1 <- next, compute M-half 1, epilogue at wrap
      if (!last) { STG_B(1, kb3); STG_A(1, kb3, Asrc); }
      MMH(1);
      if (wrap) {
        // ---- epilogue for this rep (register-only; hides under staging)
        if (rep < 2) {
          const float scale = (rep == 0) ? QSCALE : 1.0f;
          short* outw = obf + (size_t)rep * (64u * 2048u * 64u);
#pragma unroll
          for (int i = 0; i < 4; ++i) {
            const int nn = nn0 + i * 16 + quad * 4;   // qkv col, mult of 4
            const int h = nn >> 6, d = nn & 63;
#pragma unroll
            for (int j = 0; j < 4; ++j) {
              const int tg = n0 + wc * 64 + j * 16 + l15;
              const int b = tg >> 11, tt = tg & 2047;
              short4v o4;
#pragma unroll
              for (int r = 0; r < 4; ++r) o4[r] = f2bf(acc[i][j][r] * scale);
              *(short4v*)(outw + (((size_t)(b * 16 + h) * 2048 + tt) << 6) + d) = o4;
            }
          }
        } else {                                 // V -> V^T [bh][d][2048]
#pragma unroll
          for (int i = 0; i < 4; ++i) {
            const int nn = nn0 + i * 16 + quad * 4;
            const int h = nn >> 6, d = nn & 63;
#pragma unroll
            for (int j = 0; j < 4; ++j) {
              const int tg = n0 + wc * 64 + j * 16 + l15;
              const int b = tg >> 11, tt = tg & 2047;
#pragma unroll
              for (int r = 0; r < 4; ++r)
                vt[(((size_t)(b * 16 + h) * 64 + d + r) << 11) + tt] = f2bf(acc[i][j][r]);
            }
          }
        }
#pragma unroll
        for (int i = 0; i < 4; ++i)
#pragma unroll
          for (int j = 0; j < 4; ++j) acc[i][j] = (floatx4){0.f, 0.f, 0.f, 0.f};
      }
      if (!last) WV6();
      SBAR();
    }
    Ag += 1048576;                               // next wsel panel
  }
#undef STG_A
#undef STG_B
#undef LDA_ALL
#undef LDB_ALL
#undef MMH
}

// -------------------------------------------------- Wo GEMM, 4-phase (R5-measured)
// C^T = Wo^T[1024,1024] * ctx[8192,1024]^T, tile 128x256, BK=64, 512 thr.
// grid 256 = 1.0 round, fp32 float4 epilogue.
__global__ __launch_bounds__(512, 2) void gemm8W(
    const short* __restrict__ A, const short* __restrict__ B,
    float* __restrict__ of) {
  __shared__ short As[2 * 128 * 64];   // [slot][128][64]  32 KB
  __shared__ short Bs[2 * 256 * 64];   // [slot][256][64]  64 KB
  const int tid  = threadIdx.x;
  const int w    = tid >> 6, lane = tid & 63;
  const int quad = lane >> 4, l15 = lane & 15;
  const int wr   = w >> 2, wc = w & 3;          // 2 (M=128) x 4 (N=256)
  const int fx   = l15 & 7;
  const int lid  = (int)blockIdx.x;
  const int xcd  = lid & 7, idx = lid >> 3;
  const int m0   = (idx >> 2) * 128;
  const int n0   = (xcd * 4 + (idx & 3)) * 256;
  const int srow = tid >> 3;
  const int scol = ((tid & 7) ^ (srow & 7)) * 8;

  const short* Ag = A + (size_t)(m0 + srow) * 1024 + scol;
  const short* Bg = B + (size_t)(n0 + srow) * 1024 + scol;

  floatx4 acc[4][4] = {};
  short8 af[4][2], bf[4][2];

#define STG_A(slot, kb) do { \
    short* _lb = &As[(slot) * 8192 + tid * 8]; \
    const short* _gp = Ag + (kb); \
    gll16(_gp, _lb); \
    gll16(_gp + (size_t)(64 * 1024), _lb + 4096); \
  } while (0)
#define STG_B(slot, kb) do { \
    short* _lb = &Bs[(slot) * 16384 + tid * 8]; \
    const short* _gp = Bg + (kb); \
    gll16(_gp,                         _lb); \
    gll16(_gp + (size_t)( 64 * 1024), _lb + 4096); \
    gll16(_gp + (size_t)(128 * 1024), _lb + 8192); \
    gll16(_gp + (size_t)(192 * 1024), _lb + 12288); \
  } while (0)
#define LDA_ALL(slot) do { \
    _Pragma("unroll") for (int ii = 0; ii < 4; ++ii) \
    _Pragma("unroll") for (int s = 0; s < 2; ++s) \
      af[ii][s] = *(const short8*)&As[(slot) * 8192 + \
          (wr * 64 + ii * 16 + l15) * 64 + ((s * 4 + quad) ^ fx) * 8]; \
  } while (0)
#define LDB_ALL(slot) do { \
    _Pragma("unroll") for (int j = 0; j < 4; ++j) \
    _Pragma("unroll") for (int s = 0; s < 2; ++s) \
      bf[j][s] = *(const short8*)&Bs[(slot) * 16384 + \
          (wc * 64 + j * 16 + l15) * 64 + ((s * 4 + quad) ^ fx) * 8]; \
  } while (0)
#define MMH(ih) do { \
    __builtin_amdgcn_s_setprio(1); \
    _Pragma("unroll") for (int i2 = 0; i2 < 2; ++i2) \
    _Pragma("unroll") for (int j = 0; j < 4; ++j) \
    _Pragma("unroll") for (int s = 0; s < 2; ++s) \
      acc[(ih) * 2 + i2][j] = __builtin_amdgcn_mfma_f32_16x16x32_bf16( \
          af[(ih) * 2 + i2][s], bf[j][s], acc[(ih) * 2 + i2][j], 0, 0, 0); \
    __builtin_amdgcn_s_setprio(0); \
  } while (0)

  STG_B(0, 0);  STG_A(0, 0);
  STG_B(1, 64); STG_A(1, 64);
  WV6(); SBAR();

  for (int t = 0; t < 8; ++t) {
    const int kn2 = (2 * t + 2) * 64;
    const int kn3 = (2 * t + 3) * 64;
    const bool mre = (t < 7);
    LDA_ALL(0); LDB_ALL(0);
    SBAR(); WLG();
    MMH(0);
    SBAR();
    if (mre) STG_B(0, kn2);
    if (mre) STG_A(0, kn2);
    MMH(1);
    if (mre) WV6(); else WV0();
    SBAR();
    LDA_ALL(1); LDB_ALL(1);
    SBAR(); WLG();
    MMH(0);
    SBAR();
    if (mre) STG_B(1, kn3);
    if (mre) STG_A(1, kn3);
    MMH(1);
    if (mre) WV6();
    SBAR();
  }

  const int nn0 = m0 + wr * 64;
#pragma unroll
  for (int i = 0; i < 4; ++i) {
    const int nn = nn0 + i * 16 + quad * 4;    // out col, 16B aligned
#pragma unroll
    for (int j = 0; j < 4; ++j) {
      const int tg = n0 + wc * 64 + j * 16 + l15;
      float4 o4;
      o4.x = acc[i][j][0]; o4.y = acc[i][j][1];
      o4.z = acc[i][j][2]; o4.w = acc[i][j][3];
      *(float4*)(of + (size_t)tg * 1024 + nn) = o4;
    }
  }
#undef STG_A
#undef STG_B
#undef LDA_ALL
#undef LDB_ALL
#undef MMH
}

// -------------------------------------------------- flash attention (causal, transposed)
// grid (8, 64), block 512 (8 waves), 2 blocks/CU.  Block = one 256-row
// q-band (qb); waves own 32 q rows (strips A/B of 16, kf/vf reads feed
// both).  P chunk-interleaved (QK^T+PV per 32-col chunk).  R16: vfl
// ones-row fragment is data-independent (1.0 iff l15==0) -> constant reg
// frag; Vs shrunk to [64][136] (17 KB), init deleted.  LDS 55.0 KB.
__global__ __launch_bounds__(512, 4) void attn_kernel(
    const short* __restrict__ Qg, const short* __restrict__ Kg,
    const short* __restrict__ Vt, short* __restrict__ ctx) {
  __shared__ short Ks[128 * 72];       // [t_k][d]                    18.00 KB
  __shared__ short Vs[64 * 136];       // [d][t_k]                    17.00 KB
  __shared__ short Ps[8 * 32 * 40];    // per-wave [q(32)][k(32)+pad] 20.00 KB

  const int tid  = threadIdx.x;
  const int w    = tid >> 6, lane = tid & 63;
  const int quad = lane >> 4, l15 = lane & 15;
  const int bh = (int)blockIdx.x + 8 * ((int)blockIdx.y & 7);
  const int g  = (int)blockIdx.y >> 3;
  const int qb = (g < 4) ? (7 - g) : (g - 4);   // CU pairs get qb + (7-qb)
  const int b  = bh >> 4, h = bh & 15;

  const size_t base = (size_t)bh * (T_SZ * 64);
  const short* Qb  = Qg + base;
  const short* Kb  = Kg + base;
  const short* Vtb = Vt + base;
  short* Pw = &Ps[w * 1280];

  // staging (512 thr): K row skr, 32B at col skp; V row svr, 32B at col svp
  const int skr = tid >> 2, skp = (tid & 3) * 16;
  const int svr = tid >> 3, svp = (tid & 7) * 16;

  // constant ones-row A-fragment for the l-reduction MFMA:
  // A[row=l15][k] of the ones-tile = 1.0 iff l15==0.
  short8 vfl_c;
  {
    const short vv = (l15 == 0) ? (short)0x3F80 : (short)0;
#pragma unroll
    for (int j = 0; j < 8; ++j) vfl_c[j] = vv;
  }

  const int rowA = qb * 256 + w * 32;          // strip A (16 q), strip B = +16
  const int rowB = rowA + 16;
  const int ktmax = 2 * qb + 2;

  const short8 qA0 = *(const short8*)(Qb + (size_t)(rowA + l15) * 64 + quad * 8);
  const short8 qA1 = *(const short8*)(Qb + (size_t)(rowA + l15) * 64 + 32 + quad * 8);
  const short8 qB0 = *(const short8*)(Qb + (size_t)(rowB + l15) * 64 + quad * 8);
  const short8 qB1 = *(const short8*)(Qb + (size_t)(rowB + l15) * 64 + 32 + quad * 8);

  floatx4 OA[4] = {}, OB[4] = {};
  floatx4 O5A = {}, O5B = {};                  // row: l in quad0/reg0

  // preload tile 0 into registers
  short8 kR[2], vR[2];
  kR[0] = *(const short8*)(Kb + (size_t)skr * 64 + skp);
  kR[1] = *(const short8*)(Kb + (size_t)skr * 64 + skp + 8);
  vR[0] = *(const short8*)(Vtb + (size_t)svr * 2048 + svp);
  vR[1] = *(const short8*)(Vtb + (size_t)svr * 2048 + svp + 8);

  for (int kt = 0; kt < ktmax; ++kt) {
    const int k0 = kt << 7;
    __syncthreads();                           // prior tile's LDS reads done
    *(short8*)&Ks[skr * 72 + skp]     = kR[0];
    *(short8*)&Ks[skr * 72 + skp + 8] = kR[1];
    *(short8*)&Vs[svr * 136 + svp]     = vR[0];
    *(short8*)&Vs[svr * 136 + svp + 8] = vR[1];
    if (kt + 1 < ktmax) {                      // prefetch next tile
      const int kn = (kt + 1) << 7;
      kR[0] = *(const short8*)(Kb + (size_t)(kn + skr) * 64 + skp);
      kR[1] = *(const short8*)(Kb + (size_t)(kn + skr) * 64 + skp + 8);
      vR[0] = *(const short8*)(Vtb + (size_t)svr * 2048 + kn + svp);
      vR[1] = *(const short8*)(Vtb + (size_t)svr * 2048 + kn + svp + 8);
    }
    __syncthreads();                           // staged LDS visible

    const int dkA = rowA - k0;                 // wave-uniform
    if (dkA < 0) continue;                     // tail: wave idle, barriers done
    const int dkB = dkA + 16;
    const int limA = dkA + l15, limB = limA + 16;
    const int naA = min(8, (dkA >> 4) + 1), nchA = (naA + 1) >> 1;
    const int naB = min(8, (dkB >> 4) + 1), nchB = (naB + 1) >> 1;

#pragma unroll
    for (int c = 0; c < 4; ++c) {
      if (c < nchB) {
        // ---- QK^T for the chunk's two 16-col tiles -> P LDS
#pragma unroll
        for (int mm = 0; mm < 2; ++mm) {
          const int mt = 2 * c + mm;
          const int pa = l15 * 40 + mm * 16 + quad * 4;          // strip A
          const int pb = (16 + l15) * 40 + mm * 16 + quad * 4;   // strip B
          const bool aB = (mt * 16 < dkB + 16);
          const bool aA = (mt * 16 < dkA + 16);
          if (aB) {
            const short8 kf0 = *(const short8*)&Ks[(mt * 16 + l15) * 72 + quad * 8];
            const short8 kf1 = *(const short8*)&Ks[(mt * 16 + l15) * 72 + 32 + quad * 8];
            {                                  // ---- strip B
              floatx4 s = {};
              s = __builtin_amdgcn_mfma_f32_16x16x32_bf16(kf0, qB0, s, 0, 0, 0);
              s = __builtin_amdgcn_mfma_f32_16x16x32_bf16(kf1, qB1, s, 0, 0, 0);
              if (mt * 16 + 15 > dkB) {
#pragma unroll
                for (int r = 0; r < 4; ++r)
                  if (mt * 16 + quad * 4 + r > limB) s[r] = -1e30f;
              }
              floatx4 e;
#pragma unroll
              for (int r = 0; r < 4; ++r) e[r] = fexp2(s[r]);
              uint2v pd;
              pd.x = pack_bf(e[0], e[1]);
              pd.y = pack_bf(e[2], e[3]);
              *(uint2v*)&Pw[pb] = pd;
            }
            if (c < nchA) {                    // ---- strip A (reuses kf)
              if (aA) {
                floatx4 s = {};
                s = __builtin_amdgcn_mfma_f32_16x16x32_bf16(kf0, qA0, s, 0, 0, 0);
                s = __builtin_amdgcn_mfma_f32_16x16x32_bf16(kf1, qA1, s, 0, 0, 0);
                if (mt * 16 + 15 > dkA) {
#pragma unroll
                  for (int r = 0; r < 4; ++r)
                    if (mt * 16 + quad * 4 + r > limA) s[r] = -1e30f;
                }
                floatx4 e;
#pragma unroll
                for (int r = 0; r < 4; ++r) e[r] = fexp2(s[r]);
                uint2v pd;
                pd.x = pack_bf(e[0], e[1]);
                pd.y = pack_bf(e[2], e[3]);
                *(uint2v*)&Pw[pa] = pd;
              } else {
                uint2v z; z.x = 0; z.y = 0;
                *(uint2v*)&Pw[pa] = z;
              }
            }
          } else {                             // aB false => aA false (mm==1)
            uint2v z; z.x = 0; z.y = 0;
            *(uint2v*)&Pw[pb] = z;
            if (c < nchA) *(uint2v*)&Pw[pa] = z;
          }
        }
        // ---- PV for chunk c
        const int vcol = c * 32 + quad * 8;
        short8 vf[4];
#pragma unroll
        for (int dt = 0; dt < 4; ++dt)
          vf[dt] = *(const short8*)&Vs[(dt * 16 + l15) * 136 + vcol];
        const short8 pfB = *(const short8*)&Pw[(16 + l15) * 40 + quad * 8];
#pragma unroll
        for (int dt = 0; dt < 4; ++dt)
          OB[dt] = __builtin_amdgcn_mfma_f32_16x16x32_bf16(vf[dt], pfB, OB[dt], 0, 0, 0);
        O5B = __builtin_amdgcn_mfma_f32_16x16x32_bf16(vfl_c, pfB, O5B, 0, 0, 0);
        if (c < nchA) {                        // reuses vf
          const short8 pfA = *(const short8*)&Pw[l15 * 40 + quad * 8];
#pragma unroll
          for (int dt = 0; dt < 4; ++dt)
            OA[dt] = __builtin_amdgcn_mfma_f32_16x16x32_bf16(vf[dt], pfA, OA[dt], 0, 0, 0);
          O5A = __builtin_amdgcn_mfma_f32_16x16x32_bf16(vfl_c, pfA, O5A, 0, 0, 0);
        }
      }
    }
  }

  // epilogue: l = O5[0] of quad0 lane l15 (C-layout row 0 = ones-row)
  {
    const float lA = __shfl(O5A[0], l15);
    const float invA = 1.0f / lA;
    const int t = rowA + l15;
    short* cb = ctx + (((size_t)(b * T_SZ + t)) << 10) + h * 64 + quad * 4;
#pragma unroll
    for (int dt = 0; dt < 4; ++dt) {
      short4v o4;
#pragma unroll
      for (int r = 0; r < 4; ++r) o4[r] = f2bf(OA[dt][r] * invA);
      *(short4v*)(cb + dt * 16) = o4;
    }
  }
  {
    const float lB = __shfl(O5B[0], l15);
    const float invB = 1.0f / lB;
    const int t = rowB + l15;
    short* cb = ctx + (((size_t)(b * T_SZ + t)) << 10) + h * 64 + quad * 4;
#pragma unroll
    for (int dt = 0; dt < 4; ++dt) {
      short4v o4;
#pragma unroll
      for (int r = 0; r < 4; ++r) o4[r] = f2bf(OB[dt][r] * invB);
      *(short4v*)(cb + dt * 16) = o4;
    }
  }
}

// --------------------------------------------------
extern "C" void kernel_launch(void* const* d_in, const int* in_sizes, int n_in,
                              void* d_out, int out_size, void* d_ws, size_t ws_size,
                              hipStream_t stream) {
  const float* x  = (const float*)d_in[0];
  const float* Wq = (const float*)d_in[1];
  const float* Wk = (const float*)d_in[2];
  const float* Wv = (const float*)d_in[3];
  const float* Wo = (const float*)d_in[4];
  float* out = (float*)d_out;

  // bf16 workspace (72 MB):
  //   xb [8M]  : x bf16; dead after gemm_qkv3 -> reused as ctx
  //   Wt [4x1M]: transposed weights
  //   Qb,Kb [8M each] : projections [bh][t][64]
  //   Vt [8M]  : V^T [bh][64][t]  (written directly by gemm_qkv3 epilogue)
  short* ws  = (short*)d_ws;
  short* xb  = ws;
  short* Wt  = ws + 8388608;
  short* Qb  = Wt + 4 * 1048576;
  short* Kb  = Qb + 8388608;
  short* Vt  = Kb + 8388608;
  short* ctx = xb;

  cvt_kernel<<<dim3(32, 32, 5), dim3(32, 8), 0, stream>>>(Wq, Wk, Wv, Wo, Wt, x, xb);
  gemm_qkv3<<<dim3(256), 512, 0, stream>>>(Wt, xb, Qb, Vt);
  attn_kernel<<<dim3(8, 64), 512, 0, stream>>>(Qb, Kb, Vt, ctx);
  gemm8W<<<dim3(256), 512, 0, stream>>>(Wt + 3 * 1048576, ctx, out);
}

// Round 9
// 241.512 us; speedup vs baseline: 1.0435x; 1.0150x over previous
//
#include <hip/hip_runtime.h>

// ---------------------------------------------------------------------------
// MHA: out = softmax_causal((xWq)(xWk)^T / sqrt(64)) (xWv) Wo
// B=4 T=2048 D=1024 H=16 Dh=64.  All matmuls in bf16 MFMA (fp32 accum).
// R17: consolidation of measured-best components (no new structure).
//   QKV: gemm_qkvT (R4, 68.0us measured) - 8-phase BK=64, 768 blocks.
//   attn: R5-exact 8-wave chunk-interleaved (<=72.2us; R7 pipeline and R8
//         const-vfl variants both measured worse and are reverted).
//   Wo:  gemm8W 4-phase, 256 blocks = 1.0 round (~16us, R5/R8 measured).
// Experiment ledger: QKV alternatives 72.3/72.8/75.0/75.5/80.9 all lost;
// attn alternatives 76.0/~75 lost.  This build is the first to combine the
// three best-measured components in one binary.
// ---------------------------------------------------------------------------

typedef short  short8  __attribute__((ext_vector_type(8)));
typedef short  short4v __attribute__((ext_vector_type(4)));
typedef float  floatx4 __attribute__((ext_vector_type(4)));
typedef unsigned uint2v __attribute__((ext_vector_type(2)));

#define T_SZ 2048
#define DM   1024

// 0.125 (Dh^-0.5) * log2(e): softmax in base-2 domain -> native v_exp_f32
#define QSCALE 0.18033688011112042f

__device__ __forceinline__ short f2bf(float f) {
  unsigned u = __float_as_uint(f);
  u += 0x7fffu + ((u >> 16) & 1u);        // RNE
  return (short)(u >> 16);
}

#if defined(__has_builtin) && __has_builtin(__builtin_amdgcn_cvt_pk_bf16_f32)
typedef __bf16 bf16x2_t __attribute__((ext_vector_type(2)));
__device__ __forceinline__ unsigned pack_bf(float lo, float hi) {   // 1 VALU op
  return __builtin_bit_cast(unsigned, __builtin_amdgcn_cvt_pk_bf16_f32(lo, hi));
}
#else
__device__ __forceinline__ unsigned pack_bf(float lo, float hi) {   // 3 VALU ops
  return __builtin_amdgcn_perm(__float_as_uint(hi) + 0x8000u,
                               __float_as_uint(lo) + 0x8000u, 0x07060302u);
}
#endif

#if defined(__has_builtin) && __has_builtin(__builtin_amdgcn_exp2f)
__device__ __forceinline__ float fexp2(float x) { return __builtin_amdgcn_exp2f(x); }
#else
__device__ __forceinline__ float fexp2(float x) { return exp2f(x); }
#endif

__device__ __forceinline__ void gll16(const void* g, void* l) {
  __builtin_amdgcn_global_load_lds((const __attribute__((address_space(1))) void*)g,
                                   (__attribute__((address_space(3))) void*)l, 16, 0, 0);
}

#define SBAR() asm volatile("s_barrier" ::: "memory")
#define WLG()  asm volatile("s_waitcnt lgkmcnt(0)" ::: "memory")
#define WV6()  asm volatile("s_waitcnt vmcnt(6)" ::: "memory")
#define WV0()  asm volatile("s_waitcnt vmcnt(0)" ::: "memory")

// -------------------------------------------------- converts, one launch
// z in [0,4): W[z] fp32 [K,N] -> bf16 W^T [N,K]   (grid x,y = 32,32; block 32x8)
// z == 4   : x fp32 -> bf16 flat
__global__ void cvt_kernel(const float* __restrict__ s0, const float* __restrict__ s1,
                           const float* __restrict__ s2, const float* __restrict__ s3,
                           short* __restrict__ dst,
                           const float* __restrict__ x, short* __restrict__ xb) {
  const int tx = threadIdx.x, ty = threadIdx.y;       // block (32,8)
  if (blockIdx.z == 4) {                              // ---- x -> bf16
    const int tid = ty * 32 + tx;
    const int blk = blockIdx.y * 32 + blockIdx.x;     // 0..1023
    int i = (blk * 256 + tid) * 4;
#pragma unroll
    for (int j = 0; j < 8; ++j) {
      const float4 v = *(const float4*)(x + i);
      short4v o;
      o.x = f2bf(v.x); o.y = f2bf(v.y); o.z = f2bf(v.z); o.w = f2bf(v.w);
      *(short4v*)(xb + i) = o;
      i += 1048576;
    }
    return;
  }
  const float* srcs[4] = {s0, s1, s2, s3};
  const float* src = srcs[blockIdx.z];
  short* d = dst + (size_t)blockIdx.z * 1048576;
  __shared__ float tile[32][33];
  const int n_base = blockIdx.x * 32, k_base = blockIdx.y * 32;
#pragma unroll
  for (int j = 0; j < 4; ++j)
    tile[ty + j * 8][tx] = src[(size_t)(k_base + ty + j * 8) * 1024 + n_base + tx];
  __syncthreads();
#pragma unroll
  for (int j = 0; j < 4; ++j)
    d[(size_t)(n_base + ty + j * 8) * 1024 + k_base + tx] = f2bf(tile[tx][ty + j * 8]);
}

// -------------------------------------------------- QKV GEMM, transposed 8-phase
// C^T = Wt[3072,1024] * xb[8192,1024]^T.  512 thr (8 waves, 2M x 4N), BK=64.
// BM=128 (W rows m0), BN=256 (tokens n0).  768 blocks = 3 clean rounds
// @ 1 block/CU (96 KB LDS).  R4-measured best (68.0us, VGPR 88).
__global__ __launch_bounds__(512, 2) void gemm_qkvT(
    const short* __restrict__ Wt, const short* __restrict__ xb,
    short* __restrict__ obf, short* __restrict__ vt) {
  __shared__ short As[2 * 128 * 64];   // [slot][128][64]  32 KB (Wt tile)
  __shared__ short Bs[2 * 256 * 64];   // [slot][256][64]  64 KB (x tile)
  const int tid  = threadIdx.x;
  const int w    = tid >> 6, lane = tid & 63;
  const int quad = lane >> 4, l15 = lane & 15;
  const int wr   = w >> 2, wc = w & 3;          // 2 (M=128) x 4 (N=256)
  const int fx   = l15 & 7;
  const int lid  = (int)blockIdx.x;             // 768
  const int xcd  = lid & 7, idx = lid >> 3;     // idx in [0,96)
  const int m0   = (idx >> 2) * 128;            // 24 W-row tiles
  const int n0   = (xcd * 4 + (idx & 3)) * 256; // token tile
  const int srow = tid >> 3;
  const int scol = ((tid & 7) ^ (srow & 7)) * 8;

  const short* Ag = Wt + (size_t)(m0 + srow) * 1024 + scol;
  const short* Bg = xb + (size_t)(n0 + srow) * 1024 + scol;

  floatx4 acc[4][4] = {};
  short8 af[2][2], bf[4][2];

#define STG_A(slot, kb) do { \
    short* _lb = &As[(slot) * 8192 + tid * 8]; \
    gll16(Ag + (kb), _lb); \
    gll16(Ag + (size_t)(64 * 1024) + (kb), _lb + 4096); \
  } while (0)
#define STG_B(slot, h, kb) do { \
    short* _lb = &Bs[(slot) * 16384 + (h) * 8192 + tid * 8]; \
    const short* _gp = Bg + (size_t)(h) * (128 * 1024) + (kb); \
    gll16(_gp, _lb); \
    gll16(_gp + (size_t)(64 * 1024), _lb + 4096); \
  } while (0)
#define LDA2(slot, ih) do { \
    _Pragma("unroll") for (int ii = 0; ii < 2; ++ii) \
    _Pragma("unroll") for (int s = 0; s < 2; ++s) \
      af[ii][s] = *(const short8*)&As[(slot) * 8192 + \
          (wr * 64 + (ih) * 32 + ii * 16 + l15) * 64 + ((s * 4 + quad) ^ fx) * 8]; \
  } while (0)
#define LDB8(slot) do { \
    _Pragma("unroll") for (int j = 0; j < 4; ++j) \
    _Pragma("unroll") for (int s = 0; s < 2; ++s) \
      bf[j][s] = *(const short8*)&Bs[(slot) * 16384 + \
          (wc * 64 + j * 16 + l15) * 64 + ((s * 4 + quad) ^ fx) * 8]; \
  } while (0)
#define MMQ(ih, jh) do { \
    __builtin_amdgcn_s_setprio(1); \
    _Pragma("unroll") for (int ii = 0; ii < 2; ++ii) \
    _Pragma("unroll") for (int jj = 0; jj < 2; ++jj) \
    _Pragma("unroll") for (int s = 0; s < 2; ++s) \
      acc[(ih) * 2 + ii][(jh) * 2 + jj] = __builtin_amdgcn_mfma_f32_16x16x32_bf16( \
          af[ii][s], bf[(jh) * 2 + jj][s], acc[(ih) * 2 + ii][(jh) * 2 + jj], 0, 0, 0); \
    __builtin_amdgcn_s_setprio(0); \
  } while (0)

  // prologue: kt0 -> slot0, kt1 -> slot1 (12 loads); WV6 -> kt0's 6 landed.
  STG_B(0, 0, 0);  STG_B(0, 1, 0);  STG_A(0, 0);
  STG_B(1, 0, 64); STG_B(1, 1, 64); STG_A(1, 64);
  WV6(); SBAR();

  for (int t = 0; t < 8; ++t) {
    const int kn2 = (2 * t + 2) * 64;          // -> slot0
    const int kn3 = (2 * t + 3) * 64;          // -> slot1
    const bool mre = (t < 7);
    // ---- p1: read kt0 frags (i-half0 + all B)
    LDA2(0, 0); LDB8(0);
    SBAR(); WLG(); MMQ(0, 0); SBAR();
    // ---- p2
    if (mre) STG_B(0, 0, kn2);
    SBAR(); MMQ(0, 1); SBAR();
    // ---- p3
    LDA2(0, 1);
    if (mre) STG_B(0, 1, kn2);
    SBAR(); WLG(); MMQ(1, 0); SBAR();
    // ---- p4
    if (mre) { STG_A(0, kn2); WV6(); } else { WV0(); }
    SBAR(); MMQ(1, 1); SBAR();
    // ---- p5: read kt1 frags
    LDA2(1, 0); LDB8(1);
    SBAR(); WLG(); MMQ(0, 0); SBAR();
    // ---- p6
    if (mre) STG_B(1, 0, kn3);
    SBAR(); MMQ(0, 1); SBAR();
    // ---- p7
    LDA2(1, 1);
    if (mre) STG_B(1, 1, kn3);
    SBAR(); WLG(); MMQ(1, 0); SBAR();
    // ---- p8
    if (mre) { STG_A(1, kn3); WV6(); }
    SBAR(); MMQ(1, 1); SBAR();
  }

  // ---- epilogue: C^T[m=qkv col][n=token]; head-dim on quad/r -> packed Q/K.
  const int wsel = m0 >> 10;                    // 0=Q 1=K 2=V, uniform/block
  const int nn0  = (m0 & 1023) + wr * 64;
  if (wsel < 2) {
    const float scale = (wsel == 0) ? QSCALE : 1.0f;
    short* outw = obf + (size_t)wsel * (64u * 2048u * 64u);
#pragma unroll
    for (int i = 0; i < 4; ++i) {
      const int nn = nn0 + i * 16 + quad * 4;   // qkv col, mult of 4
      const int h = nn >> 6, d = nn & 63;
#pragma unroll
      for (int j = 0; j < 4; ++j) {
        const int tg = n0 + wc * 64 + j * 16 + l15;
        const int b = tg >> 11, tt = tg & 2047;
        short4v o4;
#pragma unroll
        for (int r = 0; r < 4; ++r) o4[r] = f2bf(acc[i][j][r] * scale);
        *(short4v*)(outw + (((size_t)(b * 16 + h) * 2048 + tt) << 6) + d) = o4;
      }
    }
  } else {
#pragma unroll
    for (int i = 0; i < 4; ++i) {
      const int nn = nn0 + i * 16 + quad * 4;   // v col in [0,1024)
      const int h = nn >> 6, d = nn & 63;
#pragma unroll
      for (int j = 0; j < 4; ++j) {
        const int tg = n0 + wc * 64 + j * 16 + l15;
        const int b = tg >> 11, tt = tg & 2047;
#pragma unroll
        for (int r = 0; r < 4; ++r)
          vt[(((size_t)(b * 16 + h) * 64 + d + r) << 11) + tt] = f2bf(acc[i][j][r]);
      }
    }
  }
#undef STG_A
#undef STG_B
#undef LDA2
#undef LDB8
#undef MMQ
}

// -------------------------------------------------- Wo GEMM, 4-phase (R5-measured)
// C^T = Wo^T[1024,1024] * ctx[8192,1024]^T, tile 128x256, BK=64, 512 thr.
// grid 256 = 1.0 round, fp32 float4 epilogue (~16us).
__global__ __launch_bounds__(512, 2) void gemm8W(
    const short* __restrict__ A, const short* __restrict__ B,
    float* __restrict__ of) {
  __shared__ short As[2 * 128 * 64];   // [slot][128][64]  32 KB
  __shared__ short Bs[2 * 256 * 64];   // [slot][256][64]  64 KB
  const int tid  = threadIdx.x;
  const int w    = tid >> 6, lane = tid & 63;
  const int quad = lane >> 4, l15 = lane & 15;
  const int wr   = w >> 2, wc = w & 3;          // 2 (M=128) x 4 (N=256)
  const int fx   = l15 & 7;
  const int lid  = (int)blockIdx.x;
  const int xcd  = lid & 7, idx = lid >> 3;
  const int m0   = (idx >> 2) * 128;
  const int n0   = (xcd * 4 + (idx & 3)) * 256;
  const int srow = tid >> 3;
  const int scol = ((tid & 7) ^ (srow & 7)) * 8;

  const short* Ag = A + (size_t)(m0 + srow) * 1024 + scol;
  const short* Bg = B + (size_t)(n0 + srow) * 1024 + scol;

  floatx4 acc[4][4] = {};
  short8 af[4][2], bf[4][2];

#define STG_A(slot, kb) do { \
    short* _lb = &As[(slot) * 8192 + tid * 8]; \
    const short* _gp = Ag + (kb); \
    gll16(_gp, _lb); \
    gll16(_gp + (size_t)(64 * 1024), _lb + 4096); \
  } while (0)
#define STG_B(slot, kb) do { \
    short* _lb = &Bs[(slot) * 16384 + tid * 8]; \
    const short* _gp = Bg + (kb); \
    gll16(_gp,                         _lb); \
    gll16(_gp + (size_t)( 64 * 1024), _lb + 4096); \
    gll16(_gp + (size_t)(128 * 1024), _lb + 8192); \
    gll16(_gp + (size_t)(192 * 1024), _lb + 12288); \
  } while (0)
#define LDA_ALL(slot) do { \
    _Pragma("unroll") for (int ii = 0; ii < 4; ++ii) \
    _Pragma("unroll") for (int s = 0; s < 2; ++s) \
      af[ii][s] = *(const short8*)&As[(slot) * 8192 + \
          (wr * 64 + ii * 16 + l15) * 64 + ((s * 4 + quad) ^ fx) * 8]; \
  } while (0)
#define LDB_ALL(slot) do { \
    _Pragma("unroll") for (int j = 0; j < 4; ++j) \
    _Pragma("unroll") for (int s = 0; s < 2; ++s) \
      bf[j][s] = *(const short8*)&Bs[(slot) * 16384 + \
          (wc * 64 + j * 16 + l15) * 64 + ((s * 4 + quad) ^ fx) * 8]; \
  } while (0)
#define MMH(ih) do { \
    __builtin_amdgcn_s_setprio(1); \
    _Pragma("unroll") for (int i2 = 0; i2 < 2; ++i2) \
    _Pragma("unroll") for (int j = 0; j < 4; ++j) \
    _Pragma("unroll") for (int s = 0; s < 2; ++s) \
      acc[(ih) * 2 + i2][j] = __builtin_amdgcn_mfma_f32_16x16x32_bf16( \
          af[(ih) * 2 + i2][s], bf[j][s], acc[(ih) * 2 + i2][j], 0, 0, 0); \
    __builtin_amdgcn_s_setprio(0); \
  } while (0)

  STG_B(0, 0);  STG_A(0, 0);
  STG_B(1, 64); STG_A(1, 64);
  WV6(); SBAR();

  for (int t = 0; t < 8; ++t) {
    const int kn2 = (2 * t + 2) * 64;
    const int kn3 = (2 * t + 3) * 64;
    const bool mre = (t < 7);
    LDA_ALL(0); LDB_ALL(0);
    SBAR(); WLG();
    MMH(0);
    SBAR();
    if (mre) STG_B(0, kn2);
    if (mre) STG_A(0, kn2);
    MMH(1);
    if (mre) WV6(); else WV0();
    SBAR();
    LDA_ALL(1); LDB_ALL(1);
    SBAR(); WLG();
    MMH(0);
    SBAR();
    if (mre) STG_B(1, kn3);
    if (mre) STG_A(1, kn3);
    MMH(1);
    if (mre) WV6();
    SBAR();
  }

  const int nn0 = m0 + wr * 64;
#pragma unroll
  for (int i = 0; i < 4; ++i) {
    const int nn = nn0 + i * 16 + quad * 4;    // out col, 16B aligned
#pragma unroll
    for (int j = 0; j < 4; ++j) {
      const int tg = n0 + wc * 64 + j * 16 + l15;
      float4 o4;
      o4.x = acc[i][j][0]; o4.y = acc[i][j][1];
      o4.z = acc[i][j][2]; o4.w = acc[i][j][3];
      *(float4*)(of + (size_t)tg * 1024 + nn) = o4;
    }
  }
#undef STG_A
#undef STG_B
#undef LDA_ALL
#undef LDB_ALL
#undef MMH
}

// -------------------------------------------------- flash attention (causal, transposed)
// R5-exact.  grid (8, 64), block 512 (8 waves), 2 blocks/CU (59.25 KB).
// Block = one 256-row q-band (qb); waves own 32 q rows (strips A/B of 16,
// kf/vf frag reads feed both).  All 8 waves share one staged K/V tile.
// P chunk-interleaved (QK^T+PV per 32-col chunk), Ps = 2.5 KB/wave.
// l = softmax denom via MFMA against ones-row 64 of Vs.  CU-pair balance:
// co-resident blocks get qb and 7-qb.
__global__ __launch_bounds__(512, 4) void attn_kernel(
    const short* __restrict__ Qg, const short* __restrict__ Kg,
    const short* __restrict__ Vt, short* __restrict__ ctx) {
  __shared__ short Ks[128 * 72];       // [t_k][d]                    18.00 KB
  __shared__ short Vs[80 * 136];       // [d][t_k], row 64 = ones     21.25 KB
  __shared__ short Ps[8 * 32 * 40];    // per-wave [q(32)][k(32)+pad] 20.00 KB

  const int tid  = threadIdx.x;
  const int w    = tid >> 6, lane = tid & 63;
  const int quad = lane >> 4, l15 = lane & 15;
  const int bh = (int)blockIdx.x + 8 * ((int)blockIdx.y & 7);
  const int g  = (int)blockIdx.y >> 3;
  const int qb = (g < 4) ? (7 - g) : (g - 4);   // CU pairs get qb + (7-qb)
  const int b  = bh >> 4, h = bh & 15;

  const size_t base = (size_t)bh * (T_SZ * 64);
  const short* Qb  = Qg + base;
  const short* Kb  = Kg + base;
  const short* Vtb = Vt + base;
  short* Pw = &Ps[w * 1280];

  // staging (512 thr): K row skr, 32B at col skp; V row svr, 32B at col svp
  const int skr = tid >> 2, skp = (tid & 3) * 16;
  const int svr = tid >> 3, svp = (tid & 7) * 16;

  // init Vs rows 64..79: row 64 = 1.0 (l-reduction), 65..79 = 0
  if (tid < 256) {
    const int rr = 64 + (tid >> 4), cb = (tid & 15) * 8;
    const short vv = (tid < 16) ? (short)0x3F80 : (short)0;
    short8 fill;
#pragma unroll
    for (int j = 0; j < 8; ++j) fill[j] = vv;
    *(short8*)&Vs[rr * 136 + cb] = fill;
  }

  const int rowA = qb * 256 + w * 32;          // strip A (16 q), strip B = +16
  const int rowB = rowA + 16;
  const int ktmax = 2 * qb + 2;

  const short8 qA0 = *(const short8*)(Qb + (size_t)(rowA + l15) * 64 + quad * 8);
  const short8 qA1 = *(const short8*)(Qb + (size_t)(rowA + l15) * 64 + 32 + quad * 8);
  const short8 qB0 = *(const short8*)(Qb + (size_t)(rowB + l15) * 64 + quad * 8);
  const short8 qB1 = *(const short8*)(Qb + (size_t)(rowB + l15) * 64 + 32 + quad * 8);

  floatx4 OA[4] = {}, OB[4] = {};
  floatx4 O5A = {}, O5B = {};                  // row: l in quad0/reg0

  // preload tile 0 into registers
  short8 kR[2], vR[2];
  kR[0] = *(const short8*)(Kb + (size_t)skr * 64 + skp);
  kR[1] = *(const short8*)(Kb + (size_t)skr * 64 + skp + 8);
  vR[0] = *(const short8*)(Vtb + (size_t)svr * 2048 + svp);
  vR[1] = *(const short8*)(Vtb + (size_t)svr * 2048 + svp + 8);

  for (int kt = 0; kt < ktmax; ++kt) {
    const int k0 = kt << 7;
    __syncthreads();                           // prior tile's LDS reads done
    *(short8*)&Ks[skr * 72 + skp]     = kR[0];
    *(short8*)&Ks[skr * 72 + skp + 8] = kR[1];
    *(short8*)&Vs[svr * 136 + svp]     = vR[0];
    *(short8*)&Vs[svr * 136 + svp + 8] = vR[1];
    if (kt + 1 < ktmax) {                      // prefetch next tile
      const int kn = (kt + 1) << 7;
      kR[0] = *(const short8*)(Kb + (size_t)(kn + skr) * 64 + skp);
      kR[1] = *(const short8*)(Kb + (size_t)(kn + skr) * 64 + skp + 8);
      vR[0] = *(const short8*)(Vtb + (size_t)svr * 2048 + kn + svp);
      vR[1] = *(const short8*)(Vtb + (size_t)svr * 2048 + kn + svp + 8);
    }
    __syncthreads();                           // staged LDS visible

    const int dkA = rowA - k0;                 // wave-uniform
    if (dkA < 0) continue;                     // tail: wave idle, barriers done
    const int dkB = dkA + 16;
    const int limA = dkA + l15, limB = limA + 16;
    const int naA = min(8, (dkA >> 4) + 1), nchA = (naA + 1) >> 1;
    const int naB = min(8, (dkB >> 4) + 1), nchB = (naB + 1) >> 1;

#pragma unroll
    for (int c = 0; c < 4; ++c) {
      if (c < nchB) {
        // ---- QK^T for the chunk's two 16-col tiles -> P LDS
#pragma unroll
        for (int mm = 0; mm < 2; ++mm) {
          const int mt = 2 * c + mm;
          const int pa = l15 * 40 + mm * 16 + quad * 4;          // strip A
          const int pb = (16 + l15) * 40 + mm * 16 + quad * 4;   // strip B
          const bool aB = (mt * 16 < dkB + 16);
          const bool aA = (mt * 16 < dkA + 16);
          if (aB) {
            const short8 kf0 = *(const short8*)&Ks[(mt * 16 + l15) * 72 + quad * 8];
            const short8 kf1 = *(const short8*)&Ks[(mt * 16 + l15) * 72 + 32 + quad * 8];
            {                                  // ---- strip B
              floatx4 s = {};
              s = __builtin_amdgcn_mfma_f32_16x16x32_bf16(kf0, qB0, s, 0, 0, 0);
              s = __builtin_amdgcn_mfma_f32_16x16x32_bf16(kf1, qB1, s, 0, 0, 0);
              if (mt * 16 + 15 > dkB) {
#pragma unroll
              for (int r = 0; r < 4; ++r)
                  if (mt * 16 + quad * 4 + r > limB) s[r] = -1e30f;
              }
              floatx4 e;
#pragma unroll
              for (int r = 0; r < 4; ++r) e[r] = fexp2(s[r]);
              uint2v pd;
              pd.x = pack_bf(e[0], e[1]);
              pd.y = pack_bf(e[2], e[3]);
              *(uint2v*)&Pw[pb] = pd;
            }
            if (c < nchA) {                    // ---- strip A (reuses kf)
              if (aA) {
                floatx4 s = {};
                s = __builtin_amdgcn_mfma_f32_16x16x32_bf16(kf0, qA0, s, 0, 0, 0);
                s = __builtin_amdgcn_mfma_f32_16x16x32_bf16(kf1, qA1, s, 0, 0, 0);
                if (mt * 16 + 15 > dkA) {
#pragma unroll
                  for (int r = 0; r < 4; ++r)
                    if (mt * 16 + quad * 4 + r > limA) s[r] = -1e30f;
                }
                floatx4 e;
#pragma unroll
                for (int r = 0; r < 4; ++r) e[r] = fexp2(s[r]);
                uint2v pd;
                pd.x = pack_bf(e[0], e[1]);
                pd.y = pack_bf(e[2], e[3]);
                *(uint2v*)&Pw[pa] = pd;
              } else {
                uint2v z; z.x = 0; z.y = 0;
                *(uint2v*)&Pw[pa] = z;
              }
            }
          } else {                             // aB false => aA false (mm==1)
            uint2v z; z.x = 0; z.y = 0;
            *(uint2v*)&Pw[pb] = z;
            if (c < nchA) *(uint2v*)&Pw[pa] = z;
          }
        }
        // ---- PV for chunk c
        const int vcol = c * 32 + quad * 8;
        const short8 vfl = *(const short8*)&Vs[(64 + l15) * 136 + vcol];
        short8 vf[4];
#pragma unroll
        for (int dt = 0; dt < 4; ++dt)
          vf[dt] = *(const short8*)&Vs[(dt * 16 + l15) * 136 + vcol];
        const short8 pfB = *(const short8*)&Pw[(16 + l15) * 40 + quad * 8];
#pragma unroll
        for (int dt = 0; dt < 4; ++dt)
          OB[dt] = __builtin_amdgcn_mfma_f32_16x16x32_bf16(vf[dt], pfB, OB[dt], 0, 0, 0);
        O5B = __builtin_amdgcn_mfma_f32_16x16x32_bf16(vfl, pfB, O5B, 0, 0, 0);
        if (c < nchA) {                        // reuses vf/vfl
          const short8 pfA = *(const short8*)&Pw[l15 * 40 + quad * 8];
#pragma unroll
          for (int dt = 0; dt < 4; ++dt)
            OA[dt] = __builtin_amdgcn_mfma_f32_16x16x32_bf16(vf[dt], pfA, OA[dt], 0, 0, 0);
          O5A = __builtin_amdgcn_mfma_f32_16x16x32_bf16(vfl, pfA, O5A, 0, 0, 0);
        }
      }
    }
  }

  // epilogue: l = O5[0] of quad0 lane l15 (C-layout row 0 = ones-row d=64)
  {
    const float lA = __shfl(O5A[0], l15);
    const float invA = 1.0f / lA;
    const int t = rowA + l15;
    short* cb = ctx + (((size_t)(b * T_SZ + t)) << 10) + h * 64 + quad * 4;
#pragma unroll
    for (int dt = 0; dt < 4; ++dt) {
      short4v o4;
#pragma unroll
      for (int r = 0; r < 4; ++r) o4[r] = f2bf(OA[dt][r] * invA);
      *(short4v*)(cb + dt * 16) = o4;
    }
  }
  {
    const float lB = __shfl(O5B[0], l15);
    const float invB = 1.0f / lB;
    const int t = rowB + l15;
    short* cb = ctx + (((size_t)(b * T_SZ + t)) << 10) + h * 64 + quad * 4;
#pragma unroll
    for (int dt = 0; dt < 4; ++dt) {
      short4v o4;
#pragma unroll
      for (int r = 0; r < 4; ++r) o4[r] = f2bf(OB[dt][r] * invB);
      *(short4v*)(cb + dt * 16) = o4;
    }
  }
}

// --------------------------------------------------
extern "C" void kernel_launch(void* const* d_in, const int* in_sizes, int n_in,
                              void* d_out, int out_size, void* d_ws, size_t ws_size,
                              hipStream_t stream) {
  const float* x  = (const float*)d_in[0];
  const float* Wq = (const float*)d_in[1];
  const float* Wk = (const float*)d_in[2];
  const float* Wv = (const float*)d_in[3];
  const float* Wo = (const float*)d_in[4];
  float* out = (float*)d_out;

  // bf16 workspace (72 MB):
  //   xb [8M]  : x bf16; dead after gemm_qkvT -> reused as ctx
  //   Wt [4x1M]: transposed weights
  //   Qb,Kb [8M each] : projections [bh][t][64]
  //   Vt [8M]  : V^T [bh][64][t]  (written directly by gemm_qkvT epilogue)
  short* ws  = (short*)d_ws;
  short* xb  = ws;
  short* Wt  = ws + 8388608;
  short* Qb  = Wt + 4 * 1048576;
  short* Kb  = Qb + 8388608;
  short* Vt  = Kb + 8388608;
  short* ctx = xb;

  cvt_kernel<<<dim3(32, 32, 5), dim3(32, 8), 0, stream>>>(Wq, Wk, Wv, Wo, Wt, x, xb);
  gemm_qkvT<<<dim3(768), 512, 0, stream>>>(Wt, xb, Qb, Vt);
  attn_kernel<<<dim3(8, 64), 512, 0, stream>>>(Qb, Kb, Vt, ctx);
  gemm8W<<<dim3(256), 512, 0, stream>>>(Wt + 3 * 1048576, ctx, out);
}

// Round 10
// 237.711 us; speedup vs baseline: 1.0602x; 1.0160x over previous
//
#include <hip/hip_runtime.h>

// ---------------------------------------------------------------------------
// MHA: out = softmax_causal((xWq)(xWk)^T / sqrt(64)) (xWv) Wo
// B=4 T=2048 D=1024 H=16 Dh=64.  All matmuls in bf16 MFMA (fp32 accum).
// R18 (base R9): attn P matrix moved fully in-register.  QK^T C-frag
// (lane q=l15 holds k=4*quad+r per mt) -> PV B-frag (lane needs k=8*quad..+7)
// is exactly permlane32_swap then permlane16_swap on the packed bf16 dwords:
//   (a,b) = pl32(w0,w2); (D0,D2) = pl16(a,b); same for (w1,w3) -> (D1,D3);
//   pf = [D0,D1,D2,D3]  (verified per lane-group for all 4 quads).
// Replaces 4 LDS writes + 1 b128 read + lgkm wait per strip/chunk; Ps
// (20 KB) deleted -> LDS 39.25 KB.  Fallback (#if no permlane builtins):
// R5-measured LDS path.  QKV (gemm_qkvT 68.0), Wo (gemm8W ~16), cvt
// byte-identical to R9.
// ---------------------------------------------------------------------------

typedef short  short8  __attribute__((ext_vector_type(8)));
typedef short  short4v __attribute__((ext_vector_type(4)));
typedef float  floatx4 __attribute__((ext_vector_type(4)));
typedef unsigned uint2v __attribute__((ext_vector_type(2)));
typedef unsigned uintx4 __attribute__((ext_vector_type(4)));

#define T_SZ 2048
#define DM   1024

// 0.125 (Dh^-0.5) * log2(e): softmax in base-2 domain -> native v_exp_f32
#define QSCALE 0.18033688011112042f

__device__ __forceinline__ short f2bf(float f) {
  unsigned u = __float_as_uint(f);
  u += 0x7fffu + ((u >> 16) & 1u);        // RNE
  return (short)(u >> 16);
}

#if defined(__has_builtin) && __has_builtin(__builtin_amdgcn_cvt_pk_bf16_f32)
typedef __bf16 bf16x2_t __attribute__((ext_vector_type(2)));
__device__ __forceinline__ unsigned pack_bf(float lo, float hi) {   // 1 VALU op
  return __builtin_bit_cast(unsigned, __builtin_amdgcn_cvt_pk_bf16_f32(lo, hi));
}
#else
__device__ __forceinline__ unsigned pack_bf(float lo, float hi) {   // 3 VALU ops
  return __builtin_amdgcn_perm(__float_as_uint(hi) + 0x8000u,
                               __float_as_uint(lo) + 0x8000u, 0x07060302u);
}
#endif

#if defined(__has_builtin) && __has_builtin(__builtin_amdgcn_exp2f)
__device__ __forceinline__ float fexp2(float x) { return __builtin_amdgcn_exp2f(x); }
#else
__device__ __forceinline__ float fexp2(float x) { return exp2f(x); }
#endif

#if defined(__has_builtin)
#if __has_builtin(__builtin_amdgcn_permlane32_swap) && __has_builtin(__builtin_amdgcn_permlane16_swap)
#define HAVE_PLSWAP 1
#endif
#endif

#ifdef HAVE_PLSWAP
// Build the PV B-operand fragment (8 bf16 = k 8*quad..8*quad+7 for col l15)
// from the QK^T outputs: w0,w1 = pack(e[k=4q..4q+3]) of mt even tile,
// w2,w3 = same for mt odd tile (k+16).  Verified mapping (all 4 quads):
//   (a,b) = pl32swap(wlo, whi): a = {wlo@t0, wlo@t1, whi@t0, whi@t1},
//                               b = {wlo@t2, wlo@t3, whi@t2, whi@t3}
//   (c,d) = pl16swap(a, b):     c = {wlo@t0, wlo@t2, whi@t0, whi@t2} = Dlo
//                               d = {wlo@t1, wlo@t3, whi@t1, whi@t3} = Dhi
__device__ __forceinline__ short8 pswap_build(unsigned w0, unsigned w1,
                                              unsigned w2, unsigned w3) {
  auto r02 = __builtin_amdgcn_permlane32_swap(w0, w2, false, false);
  auto r13 = __builtin_amdgcn_permlane32_swap(w1, w3, false, false);
  auto d02 = __builtin_amdgcn_permlane16_swap(r02[0], r02[1], false, false);
  auto d13 = __builtin_amdgcn_permlane16_swap(r13[0], r13[1], false, false);
  uintx4 pd;
  pd.x = d02[0]; pd.y = d13[0]; pd.z = d02[1]; pd.w = d13[1];
  return __builtin_bit_cast(short8, pd);
}
#endif

__device__ __forceinline__ void gll16(const void* g, void* l) {
  __builtin_amdgcn_global_load_lds((const __attribute__((address_space(1))) void*)g,
                                   (__attribute__((address_space(3))) void*)l, 16, 0, 0);
}

#define SBAR() asm volatile("s_barrier" ::: "memory")
#define WLG()  asm volatile("s_waitcnt lgkmcnt(0)" ::: "memory")
#define WV6()  asm volatile("s_waitcnt vmcnt(6)" ::: "memory")
#define WV0()  asm volatile("s_waitcnt vmcnt(0)" ::: "memory")

// -------------------------------------------------- converts, one launch
// z in [0,4): W[z] fp32 [K,N] -> bf16 W^T [N,K]   (grid x,y = 32,32; block 32x8)
// z == 4   : x fp32 -> bf16 flat
__global__ void cvt_kernel(const float* __restrict__ s0, const float* __restrict__ s1,
                           const float* __restrict__ s2, const float* __restrict__ s3,
                           short* __restrict__ dst,
                           const float* __restrict__ x, short* __restrict__ xb) {
  const int tx = threadIdx.x, ty = threadIdx.y;       // block (32,8)
  if (blockIdx.z == 4) {                              // ---- x -> bf16
    const int tid = ty * 32 + tx;
    const int blk = blockIdx.y * 32 + blockIdx.x;     // 0..1023
    int i = (blk * 256 + tid) * 4;
#pragma unroll
    for (int j = 0; j < 8; ++j) {
      const float4 v = *(const float4*)(x + i);
      short4v o;
      o.x = f2bf(v.x); o.y = f2bf(v.y); o.z = f2bf(v.z); o.w = f2bf(v.w);
      *(short4v*)(xb + i) = o;
      i += 1048576;
    }
    return;
  }
  const float* srcs[4] = {s0, s1, s2, s3};
  const float* src = srcs[blockIdx.z];
  short* d = dst + (size_t)blockIdx.z * 1048576;
  __shared__ float tile[32][33];
  const int n_base = blockIdx.x * 32, k_base = blockIdx.y * 32;
#pragma unroll
  for (int j = 0; j < 4; ++j)
    tile[ty + j * 8][tx] = src[(size_t)(k_base + ty + j * 8) * 1024 + n_base + tx];
  __syncthreads();
#pragma unroll
  for (int j = 0; j < 4; ++j)
    d[(size_t)(n_base + ty + j * 8) * 1024 + k_base + tx] = f2bf(tile[tx][ty + j * 8]);
}

// -------------------------------------------------- QKV GEMM, transposed 8-phase
// C^T = Wt[3072,1024] * xb[8192,1024]^T.  512 thr (8 waves, 2M x 4N), BK=64.
// BM=128 (W rows m0), BN=256 (tokens n0).  768 blocks = 3 clean rounds
// @ 1 block/CU (96 KB LDS).  R4/R9-measured best (68.0us, VGPR 88).
__global__ __launch_bounds__(512, 2) void gemm_qkvT(
    const short* __restrict__ Wt, const short* __restrict__ xb,
    short* __restrict__ obf, short* __restrict__ vt) {
  __shared__ short As[2 * 128 * 64];   // [slot][128][64]  32 KB (Wt tile)
  __shared__ short Bs[2 * 256 * 64];   // [slot][256][64]  64 KB (x tile)
  const int tid  = threadIdx.x;
  const int w    = tid >> 6, lane = tid & 63;
  const int quad = lane >> 4, l15 = lane & 15;
  const int wr   = w >> 2, wc = w & 3;          // 2 (M=128) x 4 (N=256)
  const int fx   = l15 & 7;
  const int lid  = (int)blockIdx.x;             // 768
  const int xcd  = lid & 7, idx = lid >> 3;     // idx in [0,96)
  const int m0   = (idx >> 2) * 128;            // 24 W-row tiles
  const int n0   = (xcd * 4 + (idx & 3)) * 256; // token tile
  const int srow = tid >> 3;
  const int scol = ((tid & 7) ^ (srow & 7)) * 8;

  const short* Ag = Wt + (size_t)(m0 + srow) * 1024 + scol;
  const short* Bg = xb + (size_t)(n0 + srow) * 1024 + scol;

  floatx4 acc[4][4] = {};
  short8 af[2][2], bf[4][2];

#define STG_A(slot, kb) do { \
    short* _lb = &As[(slot) * 8192 + tid * 8]; \
    gll16(Ag + (kb), _lb); \
    gll16(Ag + (size_t)(64 * 1024) + (kb), _lb + 4096); \
  } while (0)
#define STG_B(slot, h, kb) do { \
    short* _lb = &Bs[(slot) * 16384 + (h) * 8192 + tid * 8]; \
    const short* _gp = Bg + (size_t)(h) * (128 * 1024) + (kb); \
    gll16(_gp, _lb); \
    gll16(_gp + (size_t)(64 * 1024), _lb + 4096); \
  } while (0)
#define LDA2(slot, ih) do { \
    _Pragma("unroll") for (int ii = 0; ii < 2; ++ii) \
    _Pragma("unroll") for (int s = 0; s < 2; ++s) \
      af[ii][s] = *(const short8*)&As[(slot) * 8192 + \
          (wr * 64 + (ih) * 32 + ii * 16 + l15) * 64 + ((s * 4 + quad) ^ fx) * 8]; \
  } while (0)
#define LDB8(slot) do { \
    _Pragma("unroll") for (int j = 0; j < 4; ++j) \
    _Pragma("unroll") for (int s = 0; s < 2; ++s) \
      bf[j][s] = *(const short8*)&Bs[(slot) * 16384 + \
          (wc * 64 + j * 16 + l15) * 64 + ((s * 4 + quad) ^ fx) * 8]; \
  } while (0)
#define MMQ(ih, jh) do { \
    __builtin_amdgcn_s_setprio(1); \
    _Pragma("unroll") for (int ii = 0; ii < 2; ++ii) \
    _Pragma("unroll") for (int jj = 0; jj < 2; ++jj) \
    _Pragma("unroll") for (int s = 0; s < 2; ++s) \
      acc[(ih) * 2 + ii][(jh) * 2 + jj] = __builtin_amdgcn_mfma_f32_16x16x32_bf16( \
          af[ii][s], bf[(jh) * 2 + jj][s], acc[(ih) * 2 + ii][(jh) * 2 + jj], 0, 0, 0); \
    __builtin_amdgcn_s_setprio(0); \
  } while (0)

  // prologue: kt0 -> slot0, kt1 -> slot1 (12 loads); WV6 -> kt0's 6 landed.
  STG_B(0, 0, 0);  STG_B(0, 1, 0);  STG_A(0, 0);
  STG_B(1, 0, 64); STG_B(1, 1, 64); STG_A(1, 64);
  WV6(); SBAR();

  for (int t = 0; t < 8; ++t) {
    const int kn2 = (2 * t + 2) * 64;          // -> slot0
    const int kn3 = (2 * t + 3) * 64;          // -> slot1
    const bool mre = (t < 7);
    // ---- p1: read kt0 frags (i-half0 + all B)
    LDA2(0, 0); LDB8(0);
    SBAR(); WLG(); MMQ(0, 0); SBAR();
    // ---- p2
    if (mre) STG_B(0, 0, kn2);
    SBAR(); MMQ(0, 1); SBAR();
    // ---- p3
    LDA2(0, 1);
    if (mre) STG_B(0, 1, kn2);
    SBAR(); WLG(); MMQ(1, 0); SBAR();
    // ---- p4
    if (mre) { STG_A(0, kn2); WV6(); } else { WV0(); }
    SBAR(); MMQ(1, 1); SBAR();
    // ---- p5: read kt1 frags
    LDA2(1, 0); LDB8(1);
    SBAR(); WLG(); MMQ(0, 0); SBAR();
    // ---- p6
    if (mre) STG_B(1, 0, kn3);
    SBAR(); MMQ(0, 1); SBAR();
    // ---- p7
    LDA2(1, 1);
    if (mre) STG_B(1, 1, kn3);
    SBAR(); WLG(); MMQ(1, 0); SBAR();
    // ---- p8
    if (mre) { STG_A(1, kn3); WV6(); }
    SBAR(); MMQ(1, 1); SBAR();
  }

  // ---- epilogue: C^T[m=qkv col][n=token]; head-dim on quad/r -> packed Q/K.
  const int wsel = m0 >> 10;                    // 0=Q 1=K 2=V, uniform/block
  const int nn0  = (m0 & 1023) + wr * 64;
  if (wsel < 2) {
    const float scale = (wsel == 0) ? QSCALE : 1.0f;
    short* outw = obf + (size_t)wsel * (64u * 2048u * 64u);
#pragma unroll
    for (int i = 0; i < 4; ++i) {
      const int nn = nn0 + i * 16 + quad * 4;   // qkv col, mult of 4
      const int h = nn >> 6, d = nn & 63;
#pragma unroll
      for (int j = 0; j < 4; ++j) {
        const int tg = n0 + wc * 64 + j * 16 + l15;
        const int b = tg >> 11, tt = tg & 2047;
        short4v o4;
#pragma unroll
        for (int r = 0; r < 4; ++r) o4[r] = f2bf(acc[i][j][r] * scale);
        *(short4v*)(outw + (((size_t)(b * 16 + h) * 2048 + tt) << 6) + d) = o4;
      }
    }
  } else {
#pragma unroll
    for (int i = 0; i < 4; ++i) {
      const int nn = nn0 + i * 16 + quad * 4;   // v col in [0,1024)
      const int h = nn >> 6, d = nn & 63;
#pragma unroll
      for (int j = 0; j < 4; ++j) {
        const int tg = n0 + wc * 64 + j * 16 + l15;
        const int b = tg >> 11, tt = tg & 2047;
#pragma unroll
        for (int r = 0; r < 4; ++r)
          vt[(((size_t)(b * 16 + h) * 64 + d + r) << 11) + tt] = f2bf(acc[i][j][r]);
      }
    }
  }
#undef STG_A
#undef STG_B
#undef LDA2
#undef LDB8
#undef MMQ
}

// -------------------------------------------------- Wo GEMM, 4-phase (R5-measured)
// C^T = Wo^T[1024,1024] * ctx[8192,1024]^T, tile 128x256, BK=64, 512 thr.
// grid 256 = 1.0 round, fp32 float4 epilogue (~16us).
__global__ __launch_bounds__(512, 2) void gemm8W(
    const short* __restrict__ A, const short* __restrict__ B,
    float* __restrict__ of) {
  __shared__ short As[2 * 128 * 64];   // [slot][128][64]  32 KB
  __shared__ short Bs[2 * 256 * 64];   // [slot][256][64]  64 KB
  const int tid  = threadIdx.x;
  const int w    = tid >> 6, lane = tid & 63;
  const int quad = lane >> 4, l15 = lane & 15;
  const int wr   = w >> 2, wc = w & 3;          // 2 (M=128) x 4 (N=256)
  const int fx   = l15 & 7;
  const int lid  = (int)blockIdx.x;
  const int xcd  = lid & 7, idx = lid >> 3;
  const int m0   = (idx >> 2) * 128;
  const int n0   = (xcd * 4 + (idx & 3)) * 256;
  const int srow = tid >> 3;
  const int scol = ((tid & 7) ^ (srow & 7)) * 8;

  const short* Ag = A + (size_t)(m0 + srow) * 1024 + scol;
  const short* Bg = B + (size_t)(n0 + srow) * 1024 + scol;

  floatx4 acc[4][4] = {};
  short8 af[4][2], bf[4][2];

#define STG_A(slot, kb) do { \
    short* _lb = &As[(slot) * 8192 + tid * 8]; \
    const short* _gp = Ag + (kb); \
    gll16(_gp, _lb); \
    gll16(_gp + (size_t)(64 * 1024), _lb + 4096); \
  } while (0)
#define STG_B(slot, kb) do { \
    short* _lb = &Bs[(slot) * 16384 + tid * 8]; \
    const short* _gp = Bg + (kb); \
    gll16(_gp,                         _lb); \
    gll16(_gp + (size_t)( 64 * 1024), _lb + 4096); \
    gll16(_gp + (size_t)(128 * 1024), _lb + 8192); \
    gll16(_gp + (size_t)(192 * 1024), _lb + 12288); \
  } while (0)
#define LDA_ALL(slot) do { \
    _Pragma("unroll") for (int ii = 0; ii < 4; ++ii) \
    _Pragma("unroll") for (int s = 0; s < 2; ++s) \
      af[ii][s] = *(const short8*)&As[(slot) * 8192 + \
          (wr * 64 + ii * 16 + l15) * 64 + ((s * 4 + quad) ^ fx) * 8]; \
  } while (0)
#define LDB_ALL(slot) do { \
    _Pragma("unroll") for (int j = 0; j < 4; ++j) \
    _Pragma("unroll") for (int s = 0; s < 2; ++s) \
      bf[j][s] = *(const short8*)&Bs[(slot) * 16384 + \
          (wc * 64 + j * 16 + l15) * 64 + ((s * 4 + quad) ^ fx) * 8]; \
  } while (0)
#define MMH(ih) do { \
    __builtin_amdgcn_s_setprio(1); \
    _Pragma("unroll") for (int i2 = 0; i2 < 2; ++i2) \
    _Pragma("unroll") for (int j = 0; j < 4; ++j) \
    _Pragma("unroll") for (int s = 0; s < 2; ++s) \
      acc[(ih) * 2 + i2][j] = __builtin_amdgcn_mfma_f32_16x16x32_bf16( \
          af[(ih) * 2 + i2][s], bf[j][s], acc[(ih) * 2 + i2][j], 0, 0, 0); \
    __builtin_amdgcn_s_setprio(0); \
  } while (0)

  STG_B(0, 0);  STG_A(0, 0);
  STG_B(1, 64); STG_A(1, 64);
  WV6(); SBAR();

  for (int t = 0; t < 8; ++t) {
    const int kn2 = (2 * t + 2) * 64;
    const int kn3 = (2 * t + 3) * 64;
    const bool mre = (t < 7);
    LDA_ALL(0); LDB_ALL(0);
    SBAR(); WLG();
    MMH(0);
    SBAR();
    if (mre) STG_B(0, kn2);
    if (mre) STG_A(0, kn2);
    MMH(1);
    if (mre) WV6(); else WV0();
    SBAR();
    LDA_ALL(1); LDB_ALL(1);
    SBAR(); WLG();
    MMH(0);
    SBAR();
    if (mre) STG_B(1, kn3);
    if (mre) STG_A(1, kn3);
    MMH(1);
    if (mre) WV6();
    SBAR();
  }

  const int nn0 = m0 + wr * 64;
#pragma unroll
  for (int i = 0; i < 4; ++i) {
    const int nn = nn0 + i * 16 + quad * 4;    // out col, 16B aligned
#pragma unroll
    for (int j = 0; j < 4; ++j) {
      const int tg = n0 + wc * 64 + j * 16 + l15;
      float4 o4;
      o4.x = acc[i][j][0]; o4.y = acc[i][j][1];
      o4.z = acc[i][j][2]; o4.w = acc[i][j][3];
      *(float4*)(of + (size_t)tg * 1024 + nn) = o4;
    }
  }
#undef STG_A
#undef STG_B
#undef LDA_ALL
#undef LDB_ALL
#undef MMH
}

// -------------------------------------------------- flash attention (causal, transposed)
// grid (8, 64), block 512 (8 waves).  Block = one 256-row q-band (qb);
// waves own 32 q rows (strips A/B of 16, kf/vf frag reads feed both).
// R18: P in-register via cvt_pk + permlane{32,16}_swap (no Ps LDS, no
// write->read round-trip).  LDS 39.25 KB.  Fallback: R5 LDS-P path.
__global__ __launch_bounds__(512, 4) void attn_kernel(
    const short* __restrict__ Qg, const short* __restrict__ Kg,
    const short* __restrict__ Vt, short* __restrict__ ctx) {
  __shared__ short Ks[128 * 72];       // [t_k][d]                    18.00 KB
  __shared__ short Vs[80 * 136];       // [d][t_k], row 64 = ones     21.25 KB
#ifndef HAVE_PLSWAP
  __shared__ short Ps[8 * 32 * 40];    // fallback per-wave P          20.00 KB
#endif

  const int tid  = threadIdx.x;
  const int w    = tid >> 6, lane = tid & 63;
  const int quad = lane >> 4, l15 = lane & 15;
  const int bh = (int)blockIdx.x + 8 * ((int)blockIdx.y & 7);
  const int g  = (int)blockIdx.y >> 3;
  const int qb = (g < 4) ? (7 - g) : (g - 4);   // CU pairs get qb + (7-qb)
  const int b  = bh >> 4, h = bh & 15;

  const size_t base = (size_t)bh * (T_SZ * 64);
  const short* Qb  = Qg + base;
  const short* Kb  = Kg + base;
  const short* Vtb = Vt + base;
#ifndef HAVE_PLSWAP
  short* Pw = &Ps[w * 1280];
#endif

  // staging (512 thr): K row skr, 32B at col skp; V row svr, 32B at col svp
  const int skr = tid >> 2, skp = (tid & 3) * 16;
  const int svr = tid >> 3, svp = (tid & 7) * 16;

  // init Vs rows 64..79: row 64 = 1.0 (l-reduction), 65..79 = 0
  if (tid < 256) {
    const int rr = 64 + (tid >> 4), cb = (tid & 15) * 8;
    const short vv = (tid < 16) ? (short)0x3F80 : (short)0;
    short8 fill;
#pragma unroll
    for (int j = 0; j < 8; ++j) fill[j] = vv;
    *(short8*)&Vs[rr * 136 + cb] = fill;
  }

  const int rowA = qb * 256 + w * 32;          // strip A (16 q), strip B = +16
  const int rowB = rowA + 16;
  const int ktmax = 2 * qb + 2;

  const short8 qA0 = *(const short8*)(Qb + (size_t)(rowA + l15) * 64 + quad * 8);
  const short8 qA1 = *(const short8*)(Qb + (size_t)(rowA + l15) * 64 + 32 + quad * 8);
  const short8 qB0 = *(const short8*)(Qb + (size_t)(rowB + l15) * 64 + quad * 8);
  const short8 qB1 = *(const short8*)(Qb + (size_t)(rowB + l15) * 64 + 32 + quad * 8);

  floatx4 OA[4] = {}, OB[4] = {};
  floatx4 O5A = {}, O5B = {};                  // row: l in quad0/reg0

  // preload tile 0 into registers
  short8 kR[2], vR[2];
  kR[0] = *(const short8*)(Kb + (size_t)skr * 64 + skp);
  kR[1] = *(const short8*)(Kb + (size_t)skr * 64 + skp + 8);
  vR[0] = *(const short8*)(Vtb + (size_t)svr * 2048 + svp);
  vR[1] = *(const short8*)(Vtb + (size_t)svr * 2048 + svp + 8);

  for (int kt = 0; kt < ktmax; ++kt) {
    const int k0 = kt << 7;
    __syncthreads();                           // prior tile's LDS reads done
    *(short8*)&Ks[skr * 72 + skp]     = kR[0];
    *(short8*)&Ks[skr * 72 + skp + 8] = kR[1];
    *(short8*)&Vs[svr * 136 + svp]     = vR[0];
    *(short8*)&Vs[svr * 136 + svp + 8] = vR[1];
    if (kt + 1 < ktmax) {                      // prefetch next tile
      const int kn = (kt + 1) << 7;
      kR[0] = *(const short8*)(Kb + (size_t)(kn + skr) * 64 + skp);
      kR[1] = *(const short8*)(Kb + (size_t)(kn + skr) * 64 + skp + 8);
      vR[0] = *(const short8*)(Vtb + (size_t)svr * 2048 + kn + svp);
      vR[1] = *(const short8*)(Vtb + (size_t)svr * 2048 + kn + svp + 8);
    }
    __syncthreads();                           // staged LDS visible

    const int dkA = rowA - k0;                 // wave-uniform
    if (dkA < 0) continue;                     // tail: wave idle, barriers done
    const int dkB = dkA + 16;
    const int limA = dkA + l15, limB = limA + 16;
    const int naA = min(8, (dkA >> 4) + 1), nchA = (naA + 1) >> 1;
    const int naB = min(8, (dkB >> 4) + 1), nchB = (naB + 1) >> 1;

#ifdef HAVE_PLSWAP
#pragma unroll
    for (int c = 0; c < 4; ++c) {
      if (c < nchB) {
        unsigned wB0, wB1, wB2 = 0, wB3 = 0;
        unsigned wA0 = 0, wA1 = 0, wA2 = 0, wA3 = 0;
        {                                      // ---- mt = 2c (active: c<nchB)
          const int mt = 2 * c;
          const short8 kf0 = *(const short8*)&Ks[(mt * 16 + l15) * 72 + quad * 8];
          const short8 kf1 = *(const short8*)&Ks[(mt * 16 + l15) * 72 + 32 + quad * 8];
          {
            floatx4 s = {};
            s = __builtin_amdgcn_mfma_f32_16x16x32_bf16(kf0, qB0, s, 0, 0, 0);
            s = __builtin_amdgcn_mfma_f32_16x16x32_bf16(kf1, qB1, s, 0, 0, 0);
            if (mt * 16 + 15 > dkB) {
#pragma unroll
              for (int r = 0; r < 4; ++r)
                if (mt * 16 + quad * 4 + r > limB) s[r] = -1e30f;
            }
            wB0 = pack_bf(fexp2(s[0]), fexp2(s[1]));
            wB1 = pack_bf(fexp2(s[2]), fexp2(s[3]));
          }
          if (c < nchA) {                      // mt=2c < naA given c<nchA
            floatx4 s = {};
            s = __builtin_amdgcn_mfma_f32_16x16x32_bf16(kf0, qA0, s, 0, 0, 0);
            s = __builtin_amdgcn_mfma_f32_16x16x32_bf16(kf1, qA1, s, 0, 0, 0);
            if (mt * 16 + 15 > dkA) {
#pragma unroll
              for (int r = 0; r < 4; ++r)
                if (mt * 16 + quad * 4 + r > limA) s[r] = -1e30f;
            }
            wA0 = pack_bf(fexp2(s[0]), fexp2(s[1]));
            wA1 = pack_bf(fexp2(s[2]), fexp2(s[3]));
          }
        }
        if (2 * c + 1 < naB) {                 // ---- mt = 2c+1 (may be off)
          const int mt = 2 * c + 1;
          const short8 kf0 = *(const short8*)&Ks[(mt * 16 + l15) * 72 + quad * 8];
          const short8 kf1 = *(const short8*)&Ks[(mt * 16 + l15) * 72 + 32 + quad * 8];
          {
            floatx4 s = {};
            s = __builtin_amdgcn_mfma_f32_16x16x32_bf16(kf0, qB0, s, 0, 0, 0);
            s = __builtin_amdgcn_mfma_f32_16x16x32_bf16(kf1, qB1, s, 0, 0, 0);
            if (mt * 16 + 15 > dkB) {
#pragma unroll
              for (int r = 0; r < 4; ++r)
                if (mt * 16 + quad * 4 + r > limB) s[r] = -1e30f;
            }
            wB2 = pack_bf(fexp2(s[0]), fexp2(s[1]));
            wB3 = pack_bf(fexp2(s[2]), fexp2(s[3]));
          }
          if (c < nchA && mt < naA) {
            floatx4 s = {};
            s = __builtin_amdgcn_mfma_f32_16x16x32_bf16(kf0, qA0, s, 0, 0, 0);
            s = __builtin_amdgcn_mfma_f32_16x16x32_bf16(kf1, qA1, s, 0, 0, 0);
            if (mt * 16 + 15 > dkA) {
#pragma unroll
              for (int r = 0; r < 4; ++r)
                if (mt * 16 + quad * 4 + r > limA) s[r] = -1e30f;
            }
            wA2 = pack_bf(fexp2(s[0]), fexp2(s[1]));
            wA3 = pack_bf(fexp2(s[2]), fexp2(s[3]));
          }
        }
        // ---- in-register P -> PV B-frag; then PV
        const short8 pfB = pswap_build(wB0, wB1, wB2, wB3);
        const int vcol = c * 32 + quad * 8;
        const short8 vfl = *(const short8*)&Vs[(64 + l15) * 136 + vcol];
        short8 vf[4];
#pragma unroll
        for (int dt = 0; dt < 4; ++dt)
          vf[dt] = *(const short8*)&Vs[(dt * 16 + l15) * 136 + vcol];
#pragma unroll
        for (int dt = 0; dt < 4; ++dt)
          OB[dt] = __builtin_amdgcn_mfma_f32_16x16x32_bf16(vf[dt], pfB, OB[dt], 0, 0, 0);
        O5B = __builtin_amdgcn_mfma_f32_16x16x32_bf16(vfl, pfB, O5B, 0, 0, 0);
        if (c < nchA) {                        // reuses vf/vfl
          const short8 pfA = pswap_build(wA0, wA1, wA2, wA3);
#pragma unroll
          for (int dt = 0; dt < 4; ++dt)
            OA[dt] = __builtin_amdgcn_mfma_f32_16x16x32_bf16(vf[dt], pfA, OA[dt], 0, 0, 0);
          O5A = __builtin_amdgcn_mfma_f32_16x16x32_bf16(vfl, pfA, O5A, 0, 0, 0);
        }
      }
    }
#else
    // ---------------- fallback: R5-measured LDS-P path ----------------
#pragma unroll
    for (int c = 0; c < 4; ++c) {
      if (c < nchB) {
#pragma unroll
        for (int mm = 0; mm < 2; ++mm) {
          const int mt = 2 * c + mm;
          const int pa = l15 * 40 + mm * 16 + quad * 4;          // strip A
          const int pb = (16 + l15) * 40 + mm * 16 + quad * 4;   // strip B
          const bool aB = (mt * 16 < dkB + 16);
          const bool aA = (mt * 16 < dkA + 16);
          if (aB) {
            const short8 kf0 = *(const short8*)&Ks[(mt * 16 + l15) * 72 + quad * 8];
            const short8 kf1 = *(const short8*)&Ks[(mt * 16 + l15) * 72 + 32 + quad * 8];
            {
              floatx4 s = {};
              s = __builtin_amdgcn_mfma_f32_16x16x32_bf16(kf0, qB0, s, 0, 0, 0);
              s = __builtin_amdgcn_mfma_f32_16x16x32_bf16(kf1, qB1, s, 0, 0, 0);
              if (mt * 16 + 15 > dkB) {
#pragma unroll
                for (int r = 0; r < 4; ++r)
                  if (mt * 16 + quad * 4 + r > limB) s[r] = -1e30f;
              }
              floatx4 e;
#pragma unroll
              for (int r = 0; r < 4; ++r) e[r] = fexp2(s[r]);
              uint2v pd;
              pd.x = pack_bf(e[0], e[1]);
              pd.y = pack_bf(e[2], e[3]);
              *(uint2v*)&Pw[pb] = pd;
            }
            if (c < nchA) {
              if (aA) {
                floatx4 s = {};
                s = __builtin_amdgcn_mfma_f32_16x16x32_bf16(kf0, qA0, s, 0, 0, 0);
                s = __builtin_amdgcn_mfma_f32_16x16x32_bf16(kf1, qA1, s, 0, 0, 0);
                if (mt * 16 + 15 > dkA) {
#pragma unroll
                  for (int r = 0; r < 4; ++r)
                    if (mt * 16 + quad * 4 + r > limA) s[r] = -1e30f;
                }
                floatx4 e;
#pragma unroll
                for (int r = 0; r < 4; ++r) e[r] = fexp2(s[r]);
                uint2v pd;
                pd.x = pack_bf(e[0], e[1]);
                pd.y = pack_bf(e[2], e[3]);
                *(uint2v*)&Pw[pa] = pd;
              } else {
                uint2v z; z.x = 0; z.y = 0;
                *(uint2v*)&Pw[pa] = z;
              }
            }
          } else {
            uint2v z; z.x = 0; z.y = 0;
            *(uint2v*)&Pw[pb] = z;
            if (c < nchA) *(uint2v*)&Pw[pa] = z;
          }
        }
        const int vcol = c * 32 + quad * 8;
        const short8 vfl = *(const short8*)&Vs[(64 + l15) * 136 + vcol];
        short8 vf[4];
#pragma unroll
        for (int dt = 0; dt < 4; ++dt)
          vf[dt] = *(const short8*)&Vs[(dt * 16 + l15) * 136 + vcol];
        const short8 pfB = *(const short8*)&Pw[(16 + l15) * 40 + quad * 8];
#pragma unroll
        for (int dt = 0; dt < 4; ++dt)
          OB[dt] = __builtin_amdgcn_mfma_f32_16x16x32_bf16(vf[dt], pfB, OB[dt], 0, 0, 0);
        O5B = __builtin_amdgcn_mfma_f32_16x16x32_bf16(vfl, pfB, O5B, 0, 0, 0);
        if (c < nchA) {
          const short8 pfA = *(const short8*)&Pw[l15 * 40 + quad * 8];
#pragma unroll
          for (int dt = 0; dt < 4; ++dt)
            OA[dt] = __builtin_amdgcn_mfma_f32_16x16x32_bf16(vf[dt], pfA, OA[dt], 0, 0, 0);
          O5A = __builtin_amdgcn_mfma_f32_16x16x32_bf16(vfl, pfA, O5A, 0, 0, 0);
        }
      }
    }
#endif
  }

  // epilogue: l = O5[0] of quad0 lane l15 (C-layout row 0 = ones-row d=64)
  {
    const float lA = __shfl(O5A[0], l15);
    const float invA = 1.0f / lA;
    const int t = rowA + l15;
    short* cb = ctx + (((size_t)(b * T_SZ + t)) << 10) + h * 64 + quad * 4;
#pragma unroll
    for (int dt = 0; dt < 4; ++dt) {
      short4v o4;
#pragma unroll
      for (int r = 0; r < 4; ++r) o4[r] = f2bf(OA[dt][r] * invA);
      *(short4v*)(cb + dt * 16) = o4;
    }
  }
  {
    const float lB = __shfl(O5B[0], l15);
    const float invB = 1.0f / lB;
    const int t = rowB + l15;
    short* cb = ctx + (((size_t)(b * T_SZ + t)) << 10) + h * 64 + quad * 4;
#pragma unroll
    for (int dt = 0; dt < 4; ++dt) {
      short4v o4;
#pragma unroll
      for (int r = 0; r < 4; ++r) o4[r] = f2bf(OB[dt][r] * invB);
      *(short4v*)(cb + dt * 16) = o4;
    }
  }
}

// --------------------------------------------------
extern "C" void kernel_launch(void* const* d_in, const int* in_sizes, int n_in,
                              void* d_out, int out_size, void* d_ws, size_t ws_size,
                              hipStream_t stream) {
  const float* x  = (const float*)d_in[0];
  const float* Wq = (const float*)d_in[1];
  const float* Wk = (const float*)d_in[2];
  const float* Wv = (const float*)d_in[3];
  const float* Wo = (const float*)d_in[4];
  float* out = (float*)d_out;

  // bf16 workspace (72 MB):
  //   xb [8M]  : x bf16; dead after gemm_qkvT -> reused as ctx
  //   Wt [4x1M]: transposed weights
  //   Qb,Kb [8M each] : projections [bh][t][64]
  //   Vt [8M]  : V^T [bh][64][t]  (written directly by gemm_qkvT epilogue)
  short* ws  = (short*)d_ws;
  short* xb  = ws;
  short* Wt  = ws + 8388608;
  short* Qb  = Wt + 4 * 1048576;
  short* Kb  = Qb + 8388608;
  short* Vt  = Kb + 8388608;
  short* ctx = xb;

  cvt_kernel<<<dim3(32, 32, 5), dim3(32, 8), 0, stream>>>(Wq, Wk, Wv, Wo, Wt, x, xb);
  gemm_qkvT<<<dim3(768), 512, 0, stream>>>(Wt, xb, Qb, Vt);
  attn_kernel<<<dim3(8, 64), 512, 0, stream>>>(Qb, Kb, Vt, ctx);
  gemm8W<<<dim3(256), 512, 0, stream>>>(Wt + 3 * 1048576, ctx, out);
}